// Round 8
// baseline (254.999 us; speedup 1.0000x reference)
//
#include <hip/hip_runtime.h>
#include <math.h>

// SALAD head. Round 13: (a) gemm_fs double-buffered, ONE barrier per ko --
// staging (gload_lds B + cvt A + x prefetch) overlaps the MFMA phase.
// (b) sinkhorn iteration fused to one dispatch (sink_uv): coalesced
// token-major M loads (R6's A-frag-layout loads were the regression),
// v in-register, next-u partials via per-row wave shfl-LSE.
// Chain: prep, gemm_fs, sink_u, 4x sink_uv, aggregate(+v5), finalize = 9.

#define BATCH 32
#define NTOK  1025
#define DIM   768
#define KDIM  64
#define CDIM  128
#define TDIM  256
#define NM1   1024
#define ROWLEN 8448          // TDIM + KDIM*CDIM
#define NITER 5
#define INV_REG 10.0f        // 1/0.1
#define NS_AGG 8             // n-slices (128 tokens each)
#define LOG_A (-4.17438727f) // -log(65)
#define LOG_B (-6.93147181f) // -log(1024)

typedef __attribute__((ext_vector_type(8))) short short8;
typedef __attribute__((ext_vector_type(4))) float floatx4;

typedef __attribute__((address_space(3))) unsigned int lds_uint;
typedef const __attribute__((address_space(1))) unsigned int glb_uint;

__device__ __forceinline__ void gload_lds16(const void* g, void* l) {
    __builtin_amdgcn_global_load_lds((glb_uint*)g, (lds_uint*)l, 16, 0, 0);
}

__device__ __forceinline__ unsigned short bf16_rne(float f) {
    unsigned u = __builtin_bit_cast(unsigned, f);
    unsigned r = u + 0x7FFFu + ((u >> 16) & 1u);
    return (unsigned short)(r >> 16);
}

__device__ __forceinline__ short8 cvt8(float4 a, float4 b) {
    short8 r;
    r[0] = (short)bf16_rne(a.x); r[1] = (short)bf16_rne(a.y);
    r[2] = (short)bf16_rne(a.z); r[3] = (short)bf16_rne(a.w);
    r[4] = (short)bf16_rne(b.x); r[5] = (short)bf16_rne(b.y);
    r[6] = (short)bf16_rne(b.z); r[7] = (short)bf16_rne(b.w);
    return r;
}

// ---------------- prep: pack W (blocks 0..575) + t-GEMM (blocks 576..671) --
__global__ __launch_bounds__(256) void prep(
    const float* __restrict__ Wf, const float* __restrict__ Ws,
    const float* __restrict__ bf, const float* __restrict__ bs,
    const float* __restrict__ x, const float* __restrict__ Wt,
    short* __restrict__ W_pack, float* __restrict__ bias_all,
    float* __restrict__ tpart)
{
    __shared__ float xr[256];
    const int blk = blockIdx.x, tid = threadIdx.x;
    if (blk < 576) {
        int idx = blk * 256 + tid;   // < 147456 exactly
        int g    = idx / 6144;
        int rem  = idx - g * 6144;
        int nf   = rem >> 9;
        int rem2 = rem & 511;
        int lane = rem2 >> 3;
        int j    = rem2 & 7;
        int k = g * 32 + (lane >> 4) * 8 + j;
        int c = nf * 16 + (lane & 15);
        float v = (c < CDIM) ? Wf[(size_t)k * CDIM + c] : Ws[(size_t)k * KDIM + (c - CDIM)];
        W_pack[idx] = (short)bf16_rne(v);
        if (idx < 192) bias_all[idx] = (idx < CDIM) ? bf[idx] : bs[idx - CDIM];
    } else {
        int i = blk - 576;           // 0..95
        int b = i / 3, dy = i - b * 3;
        xr[tid] = x[(size_t)b * NTOK * DIM + (size_t)dy * 256 + tid];
        __syncthreads();
        float acc = 0.f;
        const float* wp = Wt + (size_t)dy * 256 * TDIM + tid;
#pragma unroll 8
        for (int d = 0; d < 256; ++d) acc = fmaf(xr[d], wp[(size_t)d * TDIM], acc);
        tpart[((size_t)dy * BATCH + b) * TDIM + tid] = acc;
    }
}

// ---------------- fused f / s GEMM: double-buffered, 1 barrier per ko ------
// blockIdx = [chunk 0..15][b 0..31] (XCD pinned). Per ko: issue stage of
// B(ko+1)+A(ko+1) into buf^1 and x(ko+2) prefetch, then MFMA on buf, then
// one __syncthreads (drains staging). Staging latency hides under MFMA.
__global__ __launch_bounds__(256, 2) void gemm_fs(
    const float* __restrict__ x, const short* __restrict__ W_pack,
    const float* __restrict__ bias_all, const float* __restrict__ sharp_p,
    unsigned short* __restrict__ fT, float* __restrict__ Mmat)
{
    __shared__ __align__(16) short Bs[2][12288];  // 48 KB
    __shared__ __align__(16) short As[2][4096];   // 16 KB
    const int tid  = threadIdx.x;
    const int wave = tid >> 6, lane = tid & 63;
    const int quad = lane >> 4, lrow = lane & 15;
    const int bb0   = blockIdx.x & 31;
    const int chunk = blockIdx.x >> 5;       // 0..15
    const int R = bb0 * 1024 + chunk * 64 + wave * 16;

    const int arow = bb0 * 1024 + chunk * 64 + (tid >> 2);
    const float* asrc = x + ((size_t)(arow >> 10) * NTOK + 1 + (arow & 1023)) * DIM + (tid & 3) * 16;
    const int r    = (tid >> 2) & 15;
    const int seg  = tid & 3;
    const int kk_w = seg >> 1;
    const int q0   = (seg & 1) * 2;
    const int aoff0 = (((tid >> 6) * 2 + kk_w) * 64 + q0 * 16 + r) * 8;
    const int aoff1 = (((tid >> 6) * 2 + kk_w) * 64 + (q0 + 1) * 16 + r) * 8;

    floatx4 acc[12];
#pragma unroll
    for (int nf = 0; nf < 12; ++nf) acc[nf] = (floatx4){0.f, 0.f, 0.f, 0.f};

    // ---- prologue: stage tile 0, prefetch x slice 1 ----
    float4 g0 = *(const float4*)(asrc);
    float4 g1 = *(const float4*)(asrc + 4);
    float4 g2 = *(const float4*)(asrc + 8);
    float4 g3 = *(const float4*)(asrc + 12);
    {
        const short* bsrc = W_pack + tid * 8;
#pragma unroll
        for (int i = 0; i < 6; ++i)
            gload_lds16(bsrc + i * 2048, &Bs[0][i * 2048 + tid * 8]);
    }
    *(short8*)&As[0][aoff0] = cvt8(g0, g1);
    *(short8*)&As[0][aoff1] = cvt8(g2, g3);
    {
        const float* ap = asrc + 64;
        g0 = *(const float4*)(ap);
        g1 = *(const float4*)(ap + 4);
        g2 = *(const float4*)(ap + 8);
        g3 = *(const float4*)(ap + 12);
    }
    __syncthreads();

    for (int ko = 0; ko < 12; ++ko) {
        const int buf = ko & 1;
        if (ko < 11) {
            // stage next B tile into the other buffer
            const short* bsrc = W_pack + (ko + 1) * 12288 + tid * 8;
#pragma unroll
            for (int i = 0; i < 6; ++i)
                gload_lds16(bsrc + i * 2048, &Bs[buf ^ 1][i * 2048 + tid * 8]);
            // next A tile from prefetched regs (wave-local LDS writes)
            *(short8*)&As[buf ^ 1][aoff0] = cvt8(g0, g1);
            *(short8*)&As[buf ^ 1][aoff1] = cvt8(g2, g3);
            if (ko < 10) {
                const float* ap = asrc + (ko + 2) * 64;
                g0 = *(const float4*)(ap);
                g1 = *(const float4*)(ap + 4);
                g2 = *(const float4*)(ap + 8);
                g3 = *(const float4*)(ap + 12);
            }
            __builtin_amdgcn_sched_barrier(0);  // staging issue stays above MFMA
        }
#pragma unroll
        for (int kk = 0; kk < 2; ++kk) {
            short8 af = *(const short8*)&As[buf][((wave * 2 + kk) * 64 + lane) * 8];
#pragma unroll
            for (int nf = 0; nf < 12; ++nf) {
                short8 bf8 = *(const short8*)&Bs[buf][((kk * 12 + nf) * 64 + lane) * 8];
                acc[nf] = __builtin_amdgcn_mfma_f32_16x16x32_bf16(af, bf8, acc[nf], 0, 0, 0);
            }
        }
        __syncthreads();
    }

    const float sc = sharp_p[0] * INV_REG;
    const int bb = R >> 10;
    const int tok = (R & 1023) + quad * 4;
#pragma unroll
    for (int nf = 0; nf < 12; ++nf) {
        const int c = nf * 16 + lrow;
        const float bias = bias_all[c];
        if (nf < 8) {
            ushort4 w;
            w.x = bf16_rne(acc[nf][0] + bias);
            w.y = bf16_rne(acc[nf][1] + bias);
            w.z = bf16_rne(acc[nf][2] + bias);
            w.w = bf16_rne(acc[nf][3] + bias);
            *(ushort4*)(fT + ((size_t)bb * CDIM + c) * NM1 + tok) = w;
        } else {
            const int k = c - CDIM;
            float4 w = make_float4((acc[nf][0] + bias) * sc, (acc[nf][1] + bias) * sc,
                                   (acc[nf][2] + bias) * sc, (acc[nf][3] + bias) * sc);
            *(float4*)(Mmat + ((size_t)bb * KDIM + k) * NM1 + tok) = w;
        }
    }
}

// ---------------- sinkhorn u1: one wave per (b,k) row, v0 = 0 --------------
// 544 blocks = [sub 0..16][b 0..31]; wave w -> k = sub*4+w (k<=64 valid).
template<bool FIRST>
__global__ __launch_bounds__(256) void sink_u(
    const float* __restrict__ Mmat, const float* __restrict__ v_in,
    const float* __restrict__ dust_p, float* __restrict__ u_out)
{
    const int b   = blockIdx.x & 31;
    const int sub = blockIdx.x >> 5;
    const int k   = sub * 4 + (threadIdx.x >> 6);
    if (k > 64) return;
    const int lane = threadIdx.x & 63;
    const float dustM = dust_p[0] * INV_REG;

    const float4* vp = (const float4*)(v_in + (size_t)b * NM1);
    float xs[16];
    if (k < 64) {
        const float4* Mp = (const float4*)(Mmat + ((size_t)b * KDIM + k) * NM1);
#pragma unroll
        for (int i = 0; i < 4; ++i) {
            float4 mv = Mp[i * 64 + lane];
            float4 vv = FIRST ? make_float4(0.f, 0.f, 0.f, 0.f) : vp[i * 64 + lane];
            xs[i * 4 + 0] = mv.x + vv.x;
            xs[i * 4 + 1] = mv.y + vv.y;
            xs[i * 4 + 2] = mv.z + vv.z;
            xs[i * 4 + 3] = mv.w + vv.w;
        }
    } else {
#pragma unroll
        for (int i = 0; i < 4; ++i) {
            float4 vv = FIRST ? make_float4(0.f, 0.f, 0.f, 0.f) : vp[i * 64 + lane];
            xs[i * 4 + 0] = dustM + vv.x;
            xs[i * 4 + 1] = dustM + vv.y;
            xs[i * 4 + 2] = dustM + vv.z;
            xs[i * 4 + 3] = dustM + vv.w;
        }
    }
    float m = xs[0];
#pragma unroll
    for (int i = 1; i < 16; ++i) m = fmaxf(m, xs[i]);
#pragma unroll
    for (int off = 1; off < 64; off <<= 1) m = fmaxf(m, __shfl_xor(m, off));
    float S = 0.f;
#pragma unroll
    for (int i = 0; i < 16; ++i) S += __expf(xs[i] - m);
#pragma unroll
    for (int off = 1; off < 64; off <<= 1) S += __shfl_xor(S, off);
    if (lane == 0) u_out[b * 65 + k] = LOG_A - (m + __logf(S));
}

// ---------------- sink_uv: one dispatch per sinkhorn iteration -------------
// grid 256 = [ns 0..7][b 0..31] x 256 thr. Thread: token tn = tid&127 of the
// slice, k-half kh = tid>>7 (32 rows in 32 VGPR, COALESCED loads). Combine
// prev u-partials (or read u directly) -> v in-register -> emit next
// u-partials via per-row wave shfl-LSE (lane==i keep trick).
template<bool UPART>
__global__ __launch_bounds__(256) void sink_uv(
    const float* __restrict__ Mmat, const float* __restrict__ dust_p,
    const float* __restrict__ u_direct, const float2* __restrict__ pin,
    float2* __restrict__ pout)
{
    __shared__ float us[65];
    __shared__ float2 xch[2][128];
    __shared__ float2 wvp[4][32];
    __shared__ float2 dsh[2];
    const int b = blockIdx.x & 31, ns = blockIdx.x >> 5;
    const int tid = threadIdx.x;
    const int tn = tid & 127;
    const int kh = tid >> 7;
    const int lane = tid & 63, wave = tid >> 6;
    const float dustM = dust_p[0] * INV_REG;

    // coalesced M loads: mreg[i] = M[b][kh*32+i][ns*128+tn]
    float mreg[32];
    const float* Mb = Mmat + ((size_t)b * KDIM + kh * 32) * NM1 + ns * 128 + tn;
#pragma unroll
    for (int i = 0; i < 32; ++i) mreg[i] = Mb[(size_t)i * NM1];

    if (tid < 65) {
        if (UPART) {
            const float2* pr = pin + (size_t)b * NS_AGG * 65 + tid;
            float2 pv[8];
            float M2 = -3.4e38f;
#pragma unroll
            for (int q = 0; q < 8; ++q) { pv[q] = pr[q * 65]; M2 = fmaxf(M2, pv[q].x); }
            float S2 = 0.f;
#pragma unroll
            for (int q = 0; q < 8; ++q) S2 += pv[q].y * __expf(pv[q].x - M2);
            us[tid] = LOG_A - (M2 + __logf(S2));
        } else {
            us[tid] = u_direct[b * 65 + tid];
        }
    }
    __syncthreads();

    // v-update for my token: partial LSE over my 32 k, exchange halves, dust
    float mm = mreg[0] + us[kh * 32];
#pragma unroll
    for (int i = 1; i < 32; ++i) mm = fmaxf(mm, mreg[i] + us[kh * 32 + i]);
    float ee = 0.f;
#pragma unroll
    for (int i = 0; i < 32; ++i) ee += __expf(mreg[i] + us[kh * 32 + i] - mm);
    xch[kh][tn] = make_float2(mm, ee);
    __syncthreads();
    float2 a0 = xch[0][tn], a1 = xch[1][tn];
    const float xd = dustM + us[64];
    float m3 = fmaxf(fmaxf(a0.x, a1.x), xd);
    float S3 = a0.y * __expf(a0.x - m3) + a1.y * __expf(a1.x - m3) + __expf(xd - m3);
    const float v = LOG_B - (m3 + __logf(S3));

    // u-partials for next iteration: per-row LSE over this wave's 64 tokens
    float rmx = 0.f, re = 0.f;
#pragma unroll
    for (int i = 0; i < 32; ++i) {
        float xv = mreg[i] + v;
        float mx = xv;
#pragma unroll
        for (int off = 1; off < 64; off <<= 1) mx = fmaxf(mx, __shfl_xor(mx, off));
        float e = __expf(xv - mx);
#pragma unroll
        for (int off = 1; off < 64; off <<= 1) e += __shfl_xor(e, off);
        if (lane == i) { rmx = mx; re = e; }
    }
    if (lane < 32) wvp[wave][lane] = make_float2(rmx, re);
    // dust row: LSE over 128 tokens of (dustM + v[t]) -- waves 0,1 hold them
    if (kh == 0) {
        float mv = v;
#pragma unroll
        for (int off = 1; off < 64; off <<= 1) mv = fmaxf(mv, __shfl_xor(mv, off));
        float ev = __expf(v - mv);
#pragma unroll
        for (int off = 1; off < 64; off <<= 1) ev += __shfl_xor(ev, off);
        if (lane == 0) dsh[wave] = make_float2(mv, ev);
    }
    __syncthreads();
    if (tid < 65) {
        float2 o;
        if (tid < 64) {
            const int w0 = (tid >> 5) * 2, i = tid & 31;
            float2 p0 = wvp[w0][i], p1 = wvp[w0 + 1][i];
            float m = fmaxf(p0.x, p1.x);
            o = make_float2(m, p0.y * __expf(p0.x - m) + p1.y * __expf(p1.x - m));
        } else {
            float2 d0 = dsh[0], d1 = dsh[1];
            float m = fmaxf(d0.x, d1.x);
            o = make_float2(dustM + m, d0.y * __expf(d0.x - m) + d1.y * __expf(d1.x - m));
        }
        pout[((size_t)b * NS_AGG + ns) * 65 + tid] = o;
    }
}

// ---------------- aggregation: u5-combine + v5 + MFMA -----------------------
// grid (BATCH, NS_AGG) x 256 thr. p = exp(M+u5+v5) -> MFMA vs fT B-frags.
__global__ __launch_bounds__(256) void aggregate(
    const float* __restrict__ Mmat, const unsigned short* __restrict__ fT,
    const float2* __restrict__ pin, const float* __restrict__ dust_p,
    float* __restrict__ vpart, float* __restrict__ rspart)
{
    __shared__ float us[65];
    __shared__ __align__(16) float vsh[128];
    __shared__ float wv[4][128][2];
    const int b = blockIdx.x, ns = blockIdx.y;
    const int tid = threadIdx.x;
    const int wave = tid >> 6, lane = tid & 63;
    const int quad = lane >> 4, lrow = lane & 15;
    const int krow = wave * 16 + lrow;
    const float dustM = dust_p[0] * INV_REG;

    // ---- u5 combine ----
    if (tid < 65) {
        const float2* pr = pin + (size_t)b * NS_AGG * 65 + tid;
        float2 pv[8];
        float M2 = -3.4e38f;
#pragma unroll
        for (int q = 0; q < 8; ++q) { pv[q] = pr[q * 65]; M2 = fmaxf(M2, pv[q].x); }
        float S2 = 0.f;
#pragma unroll
        for (int q = 0; q < 8; ++q) S2 += pv[q].y * __expf(pv[q].x - M2);
        us[tid] = LOG_A - (M2 + __logf(S2));
    }
    __syncthreads();

    // ---- M slice into registers (A-frag layout) ----
    float mreg[32];
    {
        const float* Mrow = Mmat + ((size_t)b * KDIM + krow) * NM1 + ns * 128 + quad * 8;
#pragma unroll
        for (int s = 0; s < 4; ++s) {
            float4 a = *(const float4*)(Mrow + s * 32);
            float4 c = *(const float4*)(Mrow + s * 32 + 4);
            mreg[s*8+0]=a.x; mreg[s*8+1]=a.y; mreg[s*8+2]=a.z; mreg[s*8+3]=a.w;
            mreg[s*8+4]=c.x; mreg[s*8+5]=c.y; mreg[s*8+6]=c.z; mreg[s*8+7]=c.w;
        }
    }

    // ---- fused v5: v[t] = LOG_B - LSE_k(M[k][t] + u[k]) ----
    const float uk = us[krow];
#pragma unroll
    for (int s = 0; s < 4; ++s) {
#pragma unroll
        for (int j = 0; j < 8; ++j) {
            float xv = mreg[s*8+j] + uk;
            float m2 = xv;
            m2 = fmaxf(m2, __shfl_xor(m2, 1));
            m2 = fmaxf(m2, __shfl_xor(m2, 2));
            m2 = fmaxf(m2, __shfl_xor(m2, 4));
            m2 = fmaxf(m2, __shfl_xor(m2, 8));
            float e = __expf(xv - m2);
            e += __shfl_xor(e, 1);
            e += __shfl_xor(e, 2);
            e += __shfl_xor(e, 4);
            e += __shfl_xor(e, 8);
            if (lrow == 0) {
                wv[wave][s*32 + quad*8 + j][0] = m2;
                wv[wave][s*32 + quad*8 + j][1] = e;
            }
        }
    }
    __syncthreads();
    if (tid < 128) {
        const float xd = dustM + us[64];
        float m3 = xd;
#pragma unroll
        for (int w = 0; w < 4; ++w) m3 = fmaxf(m3, wv[w][tid][0]);
        float S3 = __expf(xd - m3);
#pragma unroll
        for (int w = 0; w < 4; ++w) S3 += wv[w][tid][1] * __expf(wv[w][tid][0] - m3);
        vsh[tid] = LOG_B - (m3 + __logf(S3));
    }
    __syncthreads();

    // ---- p = exp(M+u+v) in A-frag regs, MFMA vs fT B-frags ----
    const unsigned short* fbase = fT + ((size_t)b * CDIM + lrow) * NM1 + ns * 128 + quad * 8;
    floatx4 acc[8];
#pragma unroll
    for (int nf = 0; nf < 8; ++nf) acc[nf] = (floatx4){0.f, 0.f, 0.f, 0.f};
    float rs = 0.f;
#pragma unroll
    for (int s = 0; s < 4; ++s) {
        const int tb = s * 32 + quad * 8;
        float4 v0 = *(const float4*)&vsh[tb];
        float4 v1 = *(const float4*)&vsh[tb + 4];
        float p[8];
        p[0] = __expf(mreg[s*8+0] + uk + v0.x);
        p[1] = __expf(mreg[s*8+1] + uk + v0.y);
        p[2] = __expf(mreg[s*8+2] + uk + v0.z);
        p[3] = __expf(mreg[s*8+3] + uk + v0.w);
        p[4] = __expf(mreg[s*8+4] + uk + v1.x);
        p[5] = __expf(mreg[s*8+5] + uk + v1.y);
        p[6] = __expf(mreg[s*8+6] + uk + v1.z);
        p[7] = __expf(mreg[s*8+7] + uk + v1.w);
        short8 afrag;
#pragma unroll
        for (int j = 0; j < 8; ++j) {
            rs += p[j];
            afrag[j] = (short)bf16_rne(p[j]);
        }
#pragma unroll
        for (int nf = 0; nf < 8; ++nf) {
            short8 bfrag = *(const short8*)(fbase + (size_t)nf * 16 * NM1 + s * 32);
            acc[nf] = __builtin_amdgcn_mfma_f32_16x16x32_bf16(afrag, bfrag, acc[nf], 0, 0, 0);
        }
    }
    rs += __shfl_xor(rs, 16);
    rs += __shfl_xor(rs, 32);
    if (lane < 16) rspart[(ns * BATCH + b) * KDIM + krow] = rs;

    float* vp = vpart + (size_t)(ns * BATCH + b) * (KDIM * CDIM);
#pragma unroll
    for (int nf = 0; nf < 8; ++nf) {
        const int c = nf * 16 + lrow;
#pragma unroll
        for (int j = 0; j < 4; ++j)
            vp[(size_t)(wave * 16 + quad * 4 + j) * CDIM + c] = acc[nf][j];
    }
}

// ---------------- finalize: reduce partials, anchors, L2-normalize ---------
__global__ __launch_bounds__(1024) void finalize_all(
    const float* __restrict__ vpart, const float* __restrict__ rspart,
    const float* __restrict__ anchors, const float* __restrict__ tpart,
    const float* __restrict__ bt, float* __restrict__ out)
{
    __shared__ float rstot[KDIM];
    __shared__ float red[16];
    __shared__ float sc_sh;
    const int b = blockIdx.x, tid = threadIdx.x;
    const int lane = tid & 63, wave = tid >> 6;

    if (tid < KDIM) {
        float s = 0.f;
#pragma unroll
        for (int ns = 0; ns < NS_AGG; ++ns)
            s += rspart[(ns * BATCH + b) * KDIM + tid];
        rstot[tid] = s;
    }
    __syncthreads();

    const size_t e0 = (size_t)tid * 8;
    float4 s0 = make_float4(0.f, 0.f, 0.f, 0.f);
    float4 s1 = make_float4(0.f, 0.f, 0.f, 0.f);
#pragma unroll
    for (int ns = 0; ns < NS_AGG; ++ns) {
        const float* vp = vpart + (size_t)(ns * BATCH + b) * (KDIM * CDIM) + e0;
        float4 a = *(const float4*)(vp);
        float4 c = *(const float4*)(vp + 4);
        s0.x += a.x; s0.y += a.y; s0.z += a.z; s0.w += a.w;
        s1.x += c.x; s1.y += c.y; s1.z += c.z; s1.w += c.w;
    }
    const float rsv = rstot[tid >> 4];
    float4 a0 = *(const float4*)(anchors + e0);
    float4 a1 = *(const float4*)(anchors + e0 + 4);
    float4 v0, v1;
    v0.x = 2.f * s0.x - rsv * a0.x;  v0.y = 2.f * s0.y - rsv * a0.y;
    v0.z = 2.f * s0.z - rsv * a0.z;  v0.w = 2.f * s0.w - rsv * a0.w;
    v1.x = 2.f * s1.x - rsv * a1.x;  v1.y = 2.f * s1.y - rsv * a1.y;
    v1.z = 2.f * s1.z - rsv * a1.z;  v1.w = 2.f * s1.w - rsv * a1.w;
    float ss = v0.x*v0.x + v0.y*v0.y + v0.z*v0.z + v0.w*v0.w
             + v1.x*v1.x + v1.y*v1.y + v1.z*v1.z + v1.w*v1.w;

    float t = 0.f;
    if (tid < TDIM) {
        t = bt[tid];
#pragma unroll
        for (int s = 0; s < 3; ++s) t += tpart[((size_t)s * BATCH + b) * TDIM + tid];
        ss += t * t;
    }

#pragma unroll
    for (int off = 32; off > 0; off >>= 1) ss += __shfl_down(ss, off);
    if (lane == 0) red[wave] = ss;
    __syncthreads();
    if (tid == 0) {
        float tot = 0.f;
#pragma unroll
        for (int i = 0; i < 16; ++i) tot += red[i];
        sc_sh = 1.f / fmaxf(sqrtf(tot), 1e-12f);
    }
    __syncthreads();
    const float scale = sc_sh;

    float* orow = out + (size_t)b * ROWLEN;
    if (tid < TDIM) orow[tid] = t * scale;
    v0.x *= scale; v0.y *= scale; v0.z *= scale; v0.w *= scale;
    v1.x *= scale; v1.y *= scale; v1.z *= scale; v1.w *= scale;
    *(float4*)&orow[TDIM + e0]     = v0;
    *(float4*)&orow[TDIM + e0 + 4] = v1;
}

// ---------------- launcher ----------------
extern "C" void kernel_launch(void* const* d_in, const int* in_sizes, int n_in,
                              void* d_out, int out_size, void* d_ws, size_t ws_size,
                              hipStream_t stream)
{
    const float* x       = (const float*)d_in[0];
    const float* Wf      = (const float*)d_in[1];
    const float* bf      = (const float*)d_in[2];
    const float* Ws      = (const float*)d_in[3];
    const float* bs      = (const float*)d_in[4];
    const float* Wt      = (const float*)d_in[5];
    const float* bt      = (const float*)d_in[6];
    const float* anchors = (const float*)d_in[7];
    const float* dust    = (const float*)d_in[8];
    const float* sharp   = (const float*)d_in[9];
    float* out = (float*)d_out;

    char* base = (char*)d_ws;
    short* W_pack        = (short*)base;                       // 294912 B
    float* bias_all      = (float*)(base + 294912);            // 192 fl
    float* Mmat          = bias_all + 192;                     // 2097152 fl (8.39 MB)
    unsigned short* fT   = (unsigned short*)(Mmat + (size_t)BATCH * KDIM * NM1); // 4194304 us
    float* u_buf         = (float*)(fT + (size_t)BATCH * CDIM * NM1);  // 2080 fl
    float2* partA        = (float2*)(u_buf + BATCH * 65);      // 32*8*65 f2
    float2* partB        = partA + (size_t)BATCH * NS_AGG * 65;
    float* vpart         = (float*)(partB + (size_t)BATCH * NS_AGG * 65); // 2097152 fl
    float* rspart        = vpart + (size_t)NS_AGG * BATCH * KDIM * CDIM;  // 16384 fl
    float* tpart         = rspart + NS_AGG * BATCH * KDIM;     // 24576 fl

    hipLaunchKernelGGL(prep, dim3(672), dim3(256), 0, stream,
                       Wf, Ws, bf, bs, x, Wt, W_pack, bias_all, tpart);
    hipLaunchKernelGGL(gemm_fs, dim3(512), dim3(256), 0, stream,
                       x, W_pack, bias_all, sharp, fT, Mmat);

    // u1 (v0 = 0)
    hipLaunchKernelGGL(HIP_KERNEL_NAME(sink_u<true>), dim3(544), dim3(256), 0, stream,
                       Mmat, u_buf, dust, u_buf);
    // 4 fused iterations: v_it + u_{it+1}-partials
    hipLaunchKernelGGL(HIP_KERNEL_NAME(sink_uv<false>), dim3(256), dim3(256), 0, stream,
                       Mmat, dust, u_buf, partA, partA);
    hipLaunchKernelGGL(HIP_KERNEL_NAME(sink_uv<true>), dim3(256), dim3(256), 0, stream,
                       Mmat, dust, u_buf, partA, partB);
    hipLaunchKernelGGL(HIP_KERNEL_NAME(sink_uv<true>), dim3(256), dim3(256), 0, stream,
                       Mmat, dust, u_buf, partB, partA);
    hipLaunchKernelGGL(HIP_KERNEL_NAME(sink_uv<true>), dim3(256), dim3(256), 0, stream,
                       Mmat, dust, u_buf, partA, partB);

    // u5 combine + v5 + aggregation MFMA
    hipLaunchKernelGGL(aggregate, dim3(BATCH, NS_AGG), dim3(256), 0, stream,
                       Mmat, fT, partB, dust, vpart, rspart);
    hipLaunchKernelGGL(finalize_all, dim3(BATCH), dim3(1024), 0, stream,
                       vpart, rspart, anchors, tpart, bt, out);
}

// Round 9
// 242.825 us; speedup vs baseline: 1.0501x; 1.0501x over previous
//
#include <hip/hip_runtime.h>
#include <math.h>

// SALAD head. Round 14: A/B split of R8's bundle. Solver = R7's exact chain
// (241.6us verified). gemm_fs = R8's double-buffered single-barrier version
// (change (a) isolated). If this regresses vs 241.6, (a) is reverted; if it
// improves, R8's regression was sink_uv's 384-shfl u-partial loop (b).

#define BATCH 32
#define NTOK  1025
#define DIM   768
#define KDIM  64
#define CDIM  128
#define TDIM  256
#define NM1   1024
#define ROWLEN 8448          // TDIM + KDIM*CDIM
#define NITER 5
#define INV_REG 10.0f        // 1/0.1
#define NS_AGG 8             // n-slices (128 tokens each)
#define LOG_A (-4.17438727f) // -log(65)
#define LOG_B (-6.93147181f) // -log(1024)

typedef __attribute__((ext_vector_type(8))) short short8;
typedef __attribute__((ext_vector_type(4))) float floatx4;

typedef __attribute__((address_space(3))) unsigned int lds_uint;
typedef const __attribute__((address_space(1))) unsigned int glb_uint;

__device__ __forceinline__ void gload_lds16(const void* g, void* l) {
    __builtin_amdgcn_global_load_lds((glb_uint*)g, (lds_uint*)l, 16, 0, 0);
}

__device__ __forceinline__ unsigned short bf16_rne(float f) {
    unsigned u = __builtin_bit_cast(unsigned, f);
    unsigned r = u + 0x7FFFu + ((u >> 16) & 1u);
    return (unsigned short)(r >> 16);
}

__device__ __forceinline__ short8 cvt8(float4 a, float4 b) {
    short8 r;
    r[0] = (short)bf16_rne(a.x); r[1] = (short)bf16_rne(a.y);
    r[2] = (short)bf16_rne(a.z); r[3] = (short)bf16_rne(a.w);
    r[4] = (short)bf16_rne(b.x); r[5] = (short)bf16_rne(b.y);
    r[6] = (short)bf16_rne(b.z); r[7] = (short)bf16_rne(b.w);
    return r;
}

// ---------------- prep: pack W (blocks 0..575) + t-GEMM (blocks 576..671) --
__global__ __launch_bounds__(256) void prep(
    const float* __restrict__ Wf, const float* __restrict__ Ws,
    const float* __restrict__ bf, const float* __restrict__ bs,
    const float* __restrict__ x, const float* __restrict__ Wt,
    short* __restrict__ W_pack, float* __restrict__ bias_all,
    float* __restrict__ tpart)
{
    __shared__ float xr[256];
    const int blk = blockIdx.x, tid = threadIdx.x;
    if (blk < 576) {
        int idx = blk * 256 + tid;   // < 147456 exactly
        int g    = idx / 6144;
        int rem  = idx - g * 6144;
        int nf   = rem >> 9;
        int rem2 = rem & 511;
        int lane = rem2 >> 3;
        int j    = rem2 & 7;
        int k = g * 32 + (lane >> 4) * 8 + j;
        int c = nf * 16 + (lane & 15);
        float v = (c < CDIM) ? Wf[(size_t)k * CDIM + c] : Ws[(size_t)k * KDIM + (c - CDIM)];
        W_pack[idx] = (short)bf16_rne(v);
        if (idx < 192) bias_all[idx] = (idx < CDIM) ? bf[idx] : bs[idx - CDIM];
    } else {
        int i = blk - 576;           // 0..95
        int b = i / 3, dy = i - b * 3;
        xr[tid] = x[(size_t)b * NTOK * DIM + (size_t)dy * 256 + tid];
        __syncthreads();
        float acc = 0.f;
        const float* wp = Wt + (size_t)dy * 256 * TDIM + tid;
#pragma unroll 8
        for (int d = 0; d < 256; ++d) acc = fmaf(xr[d], wp[(size_t)d * TDIM], acc);
        tpart[((size_t)dy * BATCH + b) * TDIM + tid] = acc;
    }
}

// ---------------- fused f / s GEMM: double-buffered, 1 barrier per ko ------
// blockIdx = [chunk 0..15][b 0..31] (XCD pinned). Per ko: issue stage of
// B(ko+1)+A(ko+1) into buf^1 and x(ko+2) prefetch, then MFMA on buf, then
// one __syncthreads (drains staging). Staging latency hides under MFMA.
__global__ __launch_bounds__(256, 2) void gemm_fs(
    const float* __restrict__ x, const short* __restrict__ W_pack,
    const float* __restrict__ bias_all, const float* __restrict__ sharp_p,
    unsigned short* __restrict__ fT, float* __restrict__ Mmat)
{
    __shared__ __align__(16) short Bs[2][12288];  // 48 KB
    __shared__ __align__(16) short As[2][4096];   // 16 KB
    const int tid  = threadIdx.x;
    const int wave = tid >> 6, lane = tid & 63;
    const int quad = lane >> 4, lrow = lane & 15;
    const int bb0   = blockIdx.x & 31;
    const int chunk = blockIdx.x >> 5;       // 0..15
    const int R = bb0 * 1024 + chunk * 64 + wave * 16;

    const int arow = bb0 * 1024 + chunk * 64 + (tid >> 2);
    const float* asrc = x + ((size_t)(arow >> 10) * NTOK + 1 + (arow & 1023)) * DIM + (tid & 3) * 16;
    const int r    = (tid >> 2) & 15;
    const int seg  = tid & 3;
    const int kk_w = seg >> 1;
    const int q0   = (seg & 1) * 2;
    const int aoff0 = (((tid >> 6) * 2 + kk_w) * 64 + q0 * 16 + r) * 8;
    const int aoff1 = (((tid >> 6) * 2 + kk_w) * 64 + (q0 + 1) * 16 + r) * 8;

    floatx4 acc[12];
#pragma unroll
    for (int nf = 0; nf < 12; ++nf) acc[nf] = (floatx4){0.f, 0.f, 0.f, 0.f};

    // ---- prologue: stage tile 0, prefetch x slice 1 ----
    float4 g0 = *(const float4*)(asrc);
    float4 g1 = *(const float4*)(asrc + 4);
    float4 g2 = *(const float4*)(asrc + 8);
    float4 g3 = *(const float4*)(asrc + 12);
    {
        const short* bsrc = W_pack + tid * 8;
#pragma unroll
        for (int i = 0; i < 6; ++i)
            gload_lds16(bsrc + i * 2048, &Bs[0][i * 2048 + tid * 8]);
    }
    *(short8*)&As[0][aoff0] = cvt8(g0, g1);
    *(short8*)&As[0][aoff1] = cvt8(g2, g3);
    {
        const float* ap = asrc + 64;
        g0 = *(const float4*)(ap);
        g1 = *(const float4*)(ap + 4);
        g2 = *(const float4*)(ap + 8);
        g3 = *(const float4*)(ap + 12);
    }
    __syncthreads();

    for (int ko = 0; ko < 12; ++ko) {
        const int buf = ko & 1;
        if (ko < 11) {
            // stage next B tile into the other buffer
            const short* bsrc = W_pack + (ko + 1) * 12288 + tid * 8;
#pragma unroll
            for (int i = 0; i < 6; ++i)
                gload_lds16(bsrc + i * 2048, &Bs[buf ^ 1][i * 2048 + tid * 8]);
            // next A tile from prefetched regs (wave-local LDS writes)
            *(short8*)&As[buf ^ 1][aoff0] = cvt8(g0, g1);
            *(short8*)&As[buf ^ 1][aoff1] = cvt8(g2, g3);
            if (ko < 10) {
                const float* ap = asrc + (ko + 2) * 64;
                g0 = *(const float4*)(ap);
                g1 = *(const float4*)(ap + 4);
                g2 = *(const float4*)(ap + 8);
                g3 = *(const float4*)(ap + 12);
            }
            __builtin_amdgcn_sched_barrier(0);  // staging issue stays above MFMA
        }
#pragma unroll
        for (int kk = 0; kk < 2; ++kk) {
            short8 af = *(const short8*)&As[buf][((wave * 2 + kk) * 64 + lane) * 8];
#pragma unroll
            for (int nf = 0; nf < 12; ++nf) {
                short8 bf8 = *(const short8*)&Bs[buf][((kk * 12 + nf) * 64 + lane) * 8];
                acc[nf] = __builtin_amdgcn_mfma_f32_16x16x32_bf16(af, bf8, acc[nf], 0, 0, 0);
            }
        }
        __syncthreads();
    }

    const float sc = sharp_p[0] * INV_REG;
    const int bb = R >> 10;
    const int tok = (R & 1023) + quad * 4;
#pragma unroll
    for (int nf = 0; nf < 12; ++nf) {
        const int c = nf * 16 + lrow;
        const float bias = bias_all[c];
        if (nf < 8) {
            ushort4 w;
            w.x = bf16_rne(acc[nf][0] + bias);
            w.y = bf16_rne(acc[nf][1] + bias);
            w.z = bf16_rne(acc[nf][2] + bias);
            w.w = bf16_rne(acc[nf][3] + bias);
            *(ushort4*)(fT + ((size_t)bb * CDIM + c) * NM1 + tok) = w;
        } else {
            const int k = c - CDIM;
            float4 w = make_float4((acc[nf][0] + bias) * sc, (acc[nf][1] + bias) * sc,
                                   (acc[nf][2] + bias) * sc, (acc[nf][3] + bias) * sc);
            *(float4*)(Mmat + ((size_t)bb * KDIM + k) * NM1 + tok) = w;
        }
    }
}

// ---------------- sinkhorn u-update: one wave per (b,k) row ----------------
// 544 blocks = [sub 0..16][b 0..31]; wave w -> k = sub*4+w (k<=64 valid).
template<bool FIRST>
__global__ __launch_bounds__(256) void sink_u(
    const float* __restrict__ Mmat, const float* __restrict__ v_in,
    const float* __restrict__ dust_p, float* __restrict__ u_out)
{
    const int b   = blockIdx.x & 31;
    const int sub = blockIdx.x >> 5;
    const int k   = sub * 4 + (threadIdx.x >> 6);
    if (k > 64) return;
    const int lane = threadIdx.x & 63;
    const float dustM = dust_p[0] * INV_REG;

    const float4* vp = (const float4*)(v_in + (size_t)b * NM1);
    float xs[16];
    if (k < 64) {
        const float4* Mp = (const float4*)(Mmat + ((size_t)b * KDIM + k) * NM1);
#pragma unroll
        for (int i = 0; i < 4; ++i) {
            float4 mv = Mp[i * 64 + lane];
            float4 vv = FIRST ? make_float4(0.f, 0.f, 0.f, 0.f) : vp[i * 64 + lane];
            xs[i * 4 + 0] = mv.x + vv.x;
            xs[i * 4 + 1] = mv.y + vv.y;
            xs[i * 4 + 2] = mv.z + vv.z;
            xs[i * 4 + 3] = mv.w + vv.w;
        }
    } else {
#pragma unroll
        for (int i = 0; i < 4; ++i) {
            float4 vv = FIRST ? make_float4(0.f, 0.f, 0.f, 0.f) : vp[i * 64 + lane];
            xs[i * 4 + 0] = dustM + vv.x;
            xs[i * 4 + 1] = dustM + vv.y;
            xs[i * 4 + 2] = dustM + vv.z;
            xs[i * 4 + 3] = dustM + vv.w;
        }
    }
    float m = xs[0];
#pragma unroll
    for (int i = 1; i < 16; ++i) m = fmaxf(m, xs[i]);
#pragma unroll
    for (int off = 1; off < 64; off <<= 1) m = fmaxf(m, __shfl_xor(m, off));
    float S = 0.f;
#pragma unroll
    for (int i = 0; i < 16; ++i) S += __expf(xs[i] - m);
#pragma unroll
    for (int off = 1; off < 64; off <<= 1) S += __shfl_xor(S, off);
    if (lane == 0) u_out[b * 65 + k] = LOG_A - (m + __logf(S));
}

// ---------------- sinkhorn v-update ----------------------------------------
// 512 blocks = [ns2 0..15][b 0..31] x 256 thr. Thread: token tid&63 of the
// 64-token chunk, k-quarter tid>>6. Coalesced 256B/wave loads; LDS combine.
__global__ __launch_bounds__(256) void sink_v(
    const float* __restrict__ Mmat, const float* __restrict__ u_in,
    const float* __restrict__ dust_p, float* __restrict__ v_out)
{
    __shared__ float us[65];
    __shared__ float2 pp[4][64];
    const int b   = blockIdx.x & 31;
    const int ns2 = blockIdx.x >> 5;         // 0..15
    const int tid = threadIdx.x;
    const int tok = tid & 63, kq = tid >> 6;
    const int n = ns2 * 64 + tok;
    if (tid < 65) us[tid] = u_in[b * 65 + tid];
    __syncthreads();
    const float* Mb = Mmat + ((size_t)b * KDIM + kq * 16) * NM1 + n;
    float xs[16];
#pragma unroll
    for (int kk = 0; kk < 16; ++kk) xs[kk] = Mb[(size_t)kk * NM1] + us[kq * 16 + kk];
    float m = xs[0];
#pragma unroll
    for (int kk = 1; kk < 16; ++kk) m = fmaxf(m, xs[kk]);
    float e = 0.f;
#pragma unroll
    for (int kk = 0; kk < 16; ++kk) e += __expf(xs[kk] - m);
    pp[kq][tok] = make_float2(m, e);
    __syncthreads();
    if (tid < 64) {
        const float xd = dust_p[0] * INV_REG + us[64];
        float m3 = xd;
#pragma unroll
        for (int q = 0; q < 4; ++q) m3 = fmaxf(m3, pp[q][tid].x);
        float S3 = __expf(xd - m3);
#pragma unroll
        for (int q = 0; q < 4; ++q) S3 += pp[q][tid].y * __expf(pp[q][tid].x - m3);
        v_out[(size_t)b * NM1 + ns2 * 64 + tid] = LOG_B - (m3 + __logf(S3));
    }
}

// ---------------- aggregation (with fused 5th v-update) ---------------------
// grid (BATCH, NS_AGG) x 256 thr. M-slice in A-frag regs; v5 computed
// block-locally from u5; then p = exp(M+u+v) -> MFMA vs fT B-frags.
__global__ __launch_bounds__(256) void aggregate(
    const float* __restrict__ Mmat, const unsigned short* __restrict__ fT,
    const float* __restrict__ u_in, const float* __restrict__ dust_p,
    float* __restrict__ vpart, float* __restrict__ rspart)
{
    __shared__ float us[65];
    __shared__ __align__(16) float vsh[128];
    __shared__ float wv[4][128][2];
    const int b = blockIdx.x, ns = blockIdx.y;
    const int tid = threadIdx.x;
    const int wave = tid >> 6, lane = tid & 63;
    const int quad = lane >> 4, lrow = lane & 15;
    const int krow = wave * 16 + lrow;
    const float dustM = dust_p[0] * INV_REG;

    if (tid < 65) us[tid] = u_in[b * 65 + tid];
    __syncthreads();

    // ---- M slice into registers (A-frag layout) ----
    float mreg[32];
    {
        const float* Mrow = Mmat + ((size_t)b * KDIM + krow) * NM1 + ns * 128 + quad * 8;
#pragma unroll
        for (int s = 0; s < 4; ++s) {
            float4 a = *(const float4*)(Mrow + s * 32);
            float4 c = *(const float4*)(Mrow + s * 32 + 4);
            mreg[s*8+0]=a.x; mreg[s*8+1]=a.y; mreg[s*8+2]=a.z; mreg[s*8+3]=a.w;
            mreg[s*8+4]=c.x; mreg[s*8+5]=c.y; mreg[s*8+6]=c.z; mreg[s*8+7]=c.w;
        }
    }

    // ---- fused v-update: v5[t] = LOG_B - LSE_k(M[k][t] + u[k]) ----
    const float uk = us[krow];
#pragma unroll
    for (int s = 0; s < 4; ++s) {
#pragma unroll
        for (int j = 0; j < 8; ++j) {
            float x = mreg[s*8+j] + uk;
            float m2 = x;
            m2 = fmaxf(m2, __shfl_xor(m2, 1));
            m2 = fmaxf(m2, __shfl_xor(m2, 2));
            m2 = fmaxf(m2, __shfl_xor(m2, 4));
            m2 = fmaxf(m2, __shfl_xor(m2, 8));
            float e = __expf(x - m2);
            e += __shfl_xor(e, 1);
            e += __shfl_xor(e, 2);
            e += __shfl_xor(e, 4);
            e += __shfl_xor(e, 8);
            if (lrow == 0) {
                wv[wave][s*32 + quad*8 + j][0] = m2;
                wv[wave][s*32 + quad*8 + j][1] = e;
            }
        }
    }
    __syncthreads();
    if (tid < 128) {
        const float xd = dustM + us[64];
        float m3 = xd;
#pragma unroll
        for (int w = 0; w < 4; ++w) m3 = fmaxf(m3, wv[w][tid][0]);
        float S3 = __expf(xd - m3);
#pragma unroll
        for (int w = 0; w < 4; ++w) S3 += wv[w][tid][1] * __expf(wv[w][tid][0] - m3);
        vsh[tid] = LOG_B - (m3 + __logf(S3));
    }
    __syncthreads();

    // ---- p = exp(M+u+v) in A-frag regs, MFMA vs fT B-frags ----
    const unsigned short* fbase = fT + ((size_t)b * CDIM + lrow) * NM1 + ns * 128 + quad * 8;
    floatx4 acc[8];
#pragma unroll
    for (int nf = 0; nf < 8; ++nf) acc[nf] = (floatx4){0.f, 0.f, 0.f, 0.f};
    float rs = 0.f;
#pragma unroll
    for (int s = 0; s < 4; ++s) {
        const int tb = s * 32 + quad * 8;
        float4 v0 = *(const float4*)&vsh[tb];
        float4 v1 = *(const float4*)&vsh[tb + 4];
        float p[8];
        p[0] = __expf(mreg[s*8+0] + uk + v0.x);
        p[1] = __expf(mreg[s*8+1] + uk + v0.y);
        p[2] = __expf(mreg[s*8+2] + uk + v0.z);
        p[3] = __expf(mreg[s*8+3] + uk + v0.w);
        p[4] = __expf(mreg[s*8+4] + uk + v1.x);
        p[5] = __expf(mreg[s*8+5] + uk + v1.y);
        p[6] = __expf(mreg[s*8+6] + uk + v1.z);
        p[7] = __expf(mreg[s*8+7] + uk + v1.w);
        short8 afrag;
#pragma unroll
        for (int j = 0; j < 8; ++j) {
            rs += p[j];
            afrag[j] = (short)bf16_rne(p[j]);
        }
#pragma unroll
        for (int nf = 0; nf < 8; ++nf) {
            short8 bfrag = *(const short8*)(fbase + (size_t)nf * 16 * NM1 + s * 32);
            acc[nf] = __builtin_amdgcn_mfma_f32_16x16x32_bf16(afrag, bfrag, acc[nf], 0, 0, 0);
        }
    }
    rs += __shfl_xor(rs, 16);
    rs += __shfl_xor(rs, 32);
    if (lane < 16) rspart[(ns * BATCH + b) * KDIM + krow] = rs;

    float* vp = vpart + (size_t)(ns * BATCH + b) * (KDIM * CDIM);
#pragma unroll
    for (int nf = 0; nf < 8; ++nf) {
        const int c = nf * 16 + lrow;
#pragma unroll
        for (int j = 0; j < 4; ++j)
            vp[(size_t)(wave * 16 + quad * 4 + j) * CDIM + c] = acc[nf][j];
    }
}

// ---------------- finalize: reduce partials, anchors, L2-normalize ---------
__global__ __launch_bounds__(1024) void finalize_all(
    const float* __restrict__ vpart, const float* __restrict__ rspart,
    const float* __restrict__ anchors, const float* __restrict__ tpart,
    const float* __restrict__ bt, float* __restrict__ out)
{
    __shared__ float rstot[KDIM];
    __shared__ float red[16];
    __shared__ float sc_sh;
    const int b = blockIdx.x, tid = threadIdx.x;
    const int lane = tid & 63, wave = tid >> 6;

    if (tid < KDIM) {
        float s = 0.f;
#pragma unroll
        for (int ns = 0; ns < NS_AGG; ++ns)
            s += rspart[(ns * BATCH + b) * KDIM + tid];
        rstot[tid] = s;
    }
    __syncthreads();

    const size_t e0 = (size_t)tid * 8;
    float4 s0 = make_float4(0.f, 0.f, 0.f, 0.f);
    float4 s1 = make_float4(0.f, 0.f, 0.f, 0.f);
#pragma unroll
    for (int ns = 0; ns < NS_AGG; ++ns) {
        const float* vp = vpart + (size_t)(ns * BATCH + b) * (KDIM * CDIM) + e0;
        float4 a = *(const float4*)(vp);
        float4 c = *(const float4*)(vp + 4);
        s0.x += a.x; s0.y += a.y; s0.z += a.z; s0.w += a.w;
        s1.x += c.x; s1.y += c.y; s1.z += c.z; s1.w += c.w;
    }
    const float rsv = rstot[tid >> 4];
    float4 a0 = *(const float4*)(anchors + e0);
    float4 a1 = *(const float4*)(anchors + e0 + 4);
    float4 v0, v1;
    v0.x = 2.f * s0.x - rsv * a0.x;  v0.y = 2.f * s0.y - rsv * a0.y;
    v0.z = 2.f * s0.z - rsv * a0.z;  v0.w = 2.f * s0.w - rsv * a0.w;
    v1.x = 2.f * s1.x - rsv * a1.x;  v1.y = 2.f * s1.y - rsv * a1.y;
    v1.z = 2.f * s1.z - rsv * a1.z;  v1.w = 2.f * s1.w - rsv * a1.w;
    float ss = v0.x*v0.x + v0.y*v0.y + v0.z*v0.z + v0.w*v0.w
             + v1.x*v1.x + v1.y*v1.y + v1.z*v1.z + v1.w*v1.w;

    float t = 0.f;
    if (tid < TDIM) {
        t = bt[tid];
#pragma unroll
        for (int s = 0; s < 3; ++s) t += tpart[((size_t)s * BATCH + b) * TDIM + tid];
        ss += t * t;
    }

#pragma unroll
    for (int off = 32; off > 0; off >>= 1) ss += __shfl_down(ss, off);
    if (lane == 0) red[wave] = ss;
    __syncthreads();
    if (tid == 0) {
        float tot = 0.f;
#pragma unroll
        for (int i = 0; i < 16; ++i) tot += red[i];
        sc_sh = 1.f / fmaxf(sqrtf(tot), 1e-12f);
    }
    __syncthreads();
    const float scale = sc_sh;

    float* orow = out + (size_t)b * ROWLEN;
    if (tid < TDIM) orow[tid] = t * scale;
    v0.x *= scale; v0.y *= scale; v0.z *= scale; v0.w *= scale;
    v1.x *= scale; v1.y *= scale; v1.z *= scale; v1.w *= scale;
    *(float4*)&orow[TDIM + e0]     = v0;
    *(float4*)&orow[TDIM + e0 + 4] = v1;
}

// ---------------- launcher ----------------
extern "C" void kernel_launch(void* const* d_in, const int* in_sizes, int n_in,
                              void* d_out, int out_size, void* d_ws, size_t ws_size,
                              hipStream_t stream)
{
    const float* x       = (const float*)d_in[0];
    const float* Wf      = (const float*)d_in[1];
    const float* bf      = (const float*)d_in[2];
    const float* Ws      = (const float*)d_in[3];
    const float* bs      = (const float*)d_in[4];
    const float* Wt      = (const float*)d_in[5];
    const float* bt      = (const float*)d_in[6];
    const float* anchors = (const float*)d_in[7];
    const float* dust    = (const float*)d_in[8];
    const float* sharp   = (const float*)d_in[9];
    float* out = (float*)d_out;

    char* base = (char*)d_ws;
    short* W_pack        = (short*)base;                       // 294912 B
    float* bias_all      = (float*)(base + 294912);            // 192 fl
    float* Mmat          = bias_all + 192;                     // 2097152 fl (8.39 MB)
    unsigned short* fT   = (unsigned short*)(Mmat + (size_t)BATCH * KDIM * NM1); // 4194304 us
    float* u_buf         = (float*)(fT + (size_t)BATCH * CDIM * NM1);  // 2080 fl
    float* v_buf         = u_buf + BATCH * 65;                 // 32768 fl
    float* vpart         = v_buf + BATCH * NM1;                // 2097152 fl
    float* rspart        = vpart + (size_t)NS_AGG * BATCH * KDIM * CDIM; // 16384 fl
    float* tpart         = rspart + NS_AGG * BATCH * KDIM;     // 24576 fl

    hipLaunchKernelGGL(prep, dim3(672), dim3(256), 0, stream,
                       Wf, Ws, bf, bs, x, Wt, W_pack, bias_all, tpart);
    hipLaunchKernelGGL(gemm_fs, dim3(512), dim3(256), 0, stream,
                       x, W_pack, bias_all, sharp, fT, Mmat);

    hipLaunchKernelGGL(HIP_KERNEL_NAME(sink_u<true>), dim3(544), dim3(256), 0, stream,
                       Mmat, v_buf, dust, u_buf);
    for (int it = 1; it < NITER; ++it) {
        hipLaunchKernelGGL(sink_v, dim3(512), dim3(256), 0, stream,
                           Mmat, u_buf, dust, v_buf);
        hipLaunchKernelGGL(HIP_KERNEL_NAME(sink_u<false>), dim3(544), dim3(256), 0, stream,
                           Mmat, v_buf, dust, u_buf);
    }

    hipLaunchKernelGGL(aggregate, dim3(BATCH, NS_AGG), dim3(256), 0, stream,
                       Mmat, fT, u_buf, dust, vpart, rspart);
    hipLaunchKernelGGL(finalize_all, dim3(BATCH), dim3(1024), 0, stream,
                       vpart, rspart, anchors, tpart, bt, out);
}

// Round 10
// 238.637 us; speedup vs baseline: 1.0686x; 1.0176x over previous
//
#include <hip/hip_runtime.h>
#include <math.h>

// SALAD head. Round 15: R7 chain (241.6us verified) minus the sink_u<true>
// dispatch: gemm_fs epilogue emits u1-partials (v0=0) from its accumulators
// (R6's verified epilogue, dust constant FIXED: (dustM,64) not (0,64));
// sink_v_p combines the 16 chunk-partials -> u1 in LDS then does the normal
// v-update. 12 dispatches, one fewer full M-pass.

#define BATCH 32
#define NTOK  1025
#define DIM   768
#define KDIM  64
#define CDIM  128
#define TDIM  256
#define NM1   1024
#define ROWLEN 8448          // TDIM + KDIM*CDIM
#define NITER 5
#define INV_REG 10.0f        // 1/0.1
#define NS_AGG 8             // n-slices (128 tokens each)
#define LOG_A (-4.17438727f) // -log(65)
#define LOG_B (-6.93147181f) // -log(1024)

typedef __attribute__((ext_vector_type(8))) short short8;
typedef __attribute__((ext_vector_type(4))) float floatx4;

typedef __attribute__((address_space(3))) unsigned int lds_uint;
typedef const __attribute__((address_space(1))) unsigned int glb_uint;

__device__ __forceinline__ void gload_lds16(const void* g, void* l) {
    __builtin_amdgcn_global_load_lds((glb_uint*)g, (lds_uint*)l, 16, 0, 0);
}

__device__ __forceinline__ unsigned short bf16_rne(float f) {
    unsigned u = __builtin_bit_cast(unsigned, f);
    unsigned r = u + 0x7FFFu + ((u >> 16) & 1u);
    return (unsigned short)(r >> 16);
}

__device__ __forceinline__ short8 cvt8(float4 a, float4 b) {
    short8 r;
    r[0] = (short)bf16_rne(a.x); r[1] = (short)bf16_rne(a.y);
    r[2] = (short)bf16_rne(a.z); r[3] = (short)bf16_rne(a.w);
    r[4] = (short)bf16_rne(b.x); r[5] = (short)bf16_rne(b.y);
    r[6] = (short)bf16_rne(b.z); r[7] = (short)bf16_rne(b.w);
    return r;
}

// ---------------- prep: pack W (blocks 0..575) + t-GEMM (blocks 576..671) --
__global__ __launch_bounds__(256) void prep(
    const float* __restrict__ Wf, const float* __restrict__ Ws,
    const float* __restrict__ bf, const float* __restrict__ bs,
    const float* __restrict__ x, const float* __restrict__ Wt,
    short* __restrict__ W_pack, float* __restrict__ bias_all,
    float* __restrict__ tpart)
{
    __shared__ float xr[256];
    const int blk = blockIdx.x, tid = threadIdx.x;
    if (blk < 576) {
        int idx = blk * 256 + tid;   // < 147456 exactly
        int g    = idx / 6144;
        int rem  = idx - g * 6144;
        int nf   = rem >> 9;
        int rem2 = rem & 511;
        int lane = rem2 >> 3;
        int j    = rem2 & 7;
        int k = g * 32 + (lane >> 4) * 8 + j;
        int c = nf * 16 + (lane & 15);
        float v = (c < CDIM) ? Wf[(size_t)k * CDIM + c] : Ws[(size_t)k * KDIM + (c - CDIM)];
        W_pack[idx] = (short)bf16_rne(v);
        if (idx < 192) bias_all[idx] = (idx < CDIM) ? bf[idx] : bs[idx - CDIM];
    } else {
        int i = blk - 576;           // 0..95
        int b = i / 3, dy = i - b * 3;
        xr[tid] = x[(size_t)b * NTOK * DIM + (size_t)dy * 256 + tid];
        __syncthreads();
        float acc = 0.f;
        const float* wp = Wt + (size_t)dy * 256 * TDIM + tid;
#pragma unroll 8
        for (int d = 0; d < 256; ++d) acc = fmaf(xr[d], wp[(size_t)d * TDIM], acc);
        tpart[((size_t)dy * BATCH + b) * TDIM + tid] = acc;
    }
}

// ---------------- fused f / s GEMM via MFMA + LDS staging -------------------
// R7's verified schedule (prefetch after barrier). Epilogue additionally
// emits u1-partials (row-LSE of the s-part over the block's 64 tokens, v0=0)
// into part0[b][chunk][65] (float2 m,e). Dust partial = (dustM, 64).
__global__ __launch_bounds__(256, 2) void gemm_fs(
    const float* __restrict__ x, const short* __restrict__ W_pack,
    const float* __restrict__ bias_all, const float* __restrict__ sharp_p,
    const float* __restrict__ dust_p,
    unsigned short* __restrict__ fT, float* __restrict__ Mmat,
    float2* __restrict__ part0)
{
    __shared__ __align__(16) short Bs[12288];  // 24 KB
    __shared__ __align__(16) short As[4096];   //  8 KB
    __shared__ float2 sm[4][4][16];            //  2 KB  [wave][nf-8][lrow]
    const int tid  = threadIdx.x;
    const int wave = tid >> 6, lane = tid & 63;
    const int quad = lane >> 4, lrow = lane & 15;
    const int bb0   = blockIdx.x & 31;
    const int chunk = blockIdx.x >> 5;       // 0..15
    const int R = bb0 * 1024 + chunk * 64 + wave * 16;

    const int arow = bb0 * 1024 + chunk * 64 + (tid >> 2);
    const float* asrc = x + ((size_t)(arow >> 10) * NTOK + 1 + (arow & 1023)) * DIM + (tid & 3) * 16;
    const int r    = (tid >> 2) & 15;
    const int seg  = tid & 3;
    const int kk_w = seg >> 1;
    const int q0   = (seg & 1) * 2;
    short* adst0 = &As[(((tid >> 6) * 2 + kk_w) * 64 + q0 * 16 + r) * 8];
    short* adst1 = &As[(((tid >> 6) * 2 + kk_w) * 64 + (q0 + 1) * 16 + r) * 8];

    floatx4 acc[12];
#pragma unroll
    for (int nf = 0; nf < 12; ++nf) acc[nf] = (floatx4){0.f, 0.f, 0.f, 0.f};

    float4 g0 = *(const float4*)(asrc);
    float4 g1 = *(const float4*)(asrc + 4);
    float4 g2 = *(const float4*)(asrc + 8);
    float4 g3 = *(const float4*)(asrc + 12);

    for (int ko = 0; ko < 12; ++ko) {
        __syncthreads();
        const short* bsrc = W_pack + ko * 12288 + tid * 8;
#pragma unroll
        for (int i = 0; i < 6; ++i)
            gload_lds16(bsrc + i * 2048, &Bs[i * 2048 + tid * 8]);
        *(short8*)adst0 = cvt8(g0, g1);
        *(short8*)adst1 = cvt8(g2, g3);
        __syncthreads();
        if (ko < 11) {
            // prefetch next x k-slice after the barrier: HBM latency overlaps
            // the MFMA phase; drained by NEXT iteration's barrier.
            const float* ap = asrc + (ko + 1) * 64;
            g0 = *(const float4*)(ap);
            g1 = *(const float4*)(ap + 4);
            g2 = *(const float4*)(ap + 8);
            g3 = *(const float4*)(ap + 12);
            __builtin_amdgcn_sched_barrier(0);  // loads may not sink below
        }
#pragma unroll
        for (int kk = 0; kk < 2; ++kk) {
            short8 af = *(const short8*)&As[((wave * 2 + kk) * 64 + lane) * 8];
#pragma unroll
            for (int nf = 0; nf < 12; ++nf) {
                short8 bf8 = *(const short8*)&Bs[((kk * 12 + nf) * 64 + lane) * 8];
                acc[nf] = __builtin_amdgcn_mfma_f32_16x16x32_bf16(af, bf8, acc[nf], 0, 0, 0);
            }
        }
    }

    const float sc = sharp_p[0] * INV_REG;
    const float dustM = dust_p[0] * INV_REG;
    const int bb = R >> 10;
    const int tok = (R & 1023) + quad * 4;
#pragma unroll
    for (int nf = 0; nf < 12; ++nf) {
        const int c = nf * 16 + lrow;
        const float bias = bias_all[c];
        if (nf < 8) {
            ushort4 w;
            w.x = bf16_rne(acc[nf][0] + bias);
            w.y = bf16_rne(acc[nf][1] + bias);
            w.z = bf16_rne(acc[nf][2] + bias);
            w.w = bf16_rne(acc[nf][3] + bias);
            *(ushort4*)(fT + ((size_t)bb * CDIM + c) * NM1 + tok) = w;
        } else {
            const int k = c - CDIM;
            float4 w = make_float4((acc[nf][0] + bias) * sc, (acc[nf][1] + bias) * sc,
                                   (acc[nf][2] + bias) * sc, (acc[nf][3] + bias) * sc);
            *(float4*)(Mmat + ((size_t)bb * KDIM + k) * NM1 + tok) = w;
            // u1-partial: row-LSE over this wave's 16 tokens (v0 = 0)
            float m = fmaxf(fmaxf(w.x, w.y), fmaxf(w.z, w.w));
            m = fmaxf(m, __shfl_xor(m, 16));
            m = fmaxf(m, __shfl_xor(m, 32));
            float e = __expf(w.x - m) + __expf(w.y - m)
                    + __expf(w.z - m) + __expf(w.w - m);
            e += __shfl_xor(e, 16);
            e += __shfl_xor(e, 32);
            if (quad == 0) sm[wave][nf - 8][lrow] = make_float2(m, e);
        }
    }
    __syncthreads();
    // combine 4 wave-partials (64 tokens) -> part0[b][chunk][k]
    if (tid < 65) {
        float2 o;
        if (tid < 64) {
            float2 p0 = sm[0][tid >> 4][tid & 15];
            float2 p1 = sm[1][tid >> 4][tid & 15];
            float2 p2 = sm[2][tid >> 4][tid & 15];
            float2 p3 = sm[3][tid >> 4][tid & 15];
            float m = fmaxf(fmaxf(p0.x, p1.x), fmaxf(p2.x, p3.x));
            float e = p0.y * __expf(p0.x - m) + p1.y * __expf(p1.x - m)
                    + p2.y * __expf(p2.x - m) + p3.y * __expf(p3.x - m);
            o = make_float2(m, e);
        } else {
            o = make_float2(dustM, 64.f);   // dust row, v0=0: 64 tokens exp(0)
        }
        part0[((size_t)bb0 * 16 + chunk) * 65 + tid] = o;
    }
}

// ---------------- sinkhorn u-update: one wave per (b,k) row ----------------
// 544 blocks = [sub 0..16][b 0..31]; wave w -> k = sub*4+w (k<=64 valid).
__global__ __launch_bounds__(256) void sink_u(
    const float* __restrict__ Mmat, const float* __restrict__ v_in,
    const float* __restrict__ dust_p, float* __restrict__ u_out)
{
    const int b   = blockIdx.x & 31;
    const int sub = blockIdx.x >> 5;
    const int k   = sub * 4 + (threadIdx.x >> 6);
    if (k > 64) return;
    const int lane = threadIdx.x & 63;
    const float dustM = dust_p[0] * INV_REG;

    const float4* vp = (const float4*)(v_in + (size_t)b * NM1);
    float xs[16];
    if (k < 64) {
        const float4* Mp = (const float4*)(Mmat + ((size_t)b * KDIM + k) * NM1);
#pragma unroll
        for (int i = 0; i < 4; ++i) {
            float4 mv = Mp[i * 64 + lane];
            float4 vv = vp[i * 64 + lane];
            xs[i * 4 + 0] = mv.x + vv.x;
            xs[i * 4 + 1] = mv.y + vv.y;
            xs[i * 4 + 2] = mv.z + vv.z;
            xs[i * 4 + 3] = mv.w + vv.w;
        }
    } else {
#pragma unroll
        for (int i = 0; i < 4; ++i) {
            float4 vv = vp[i * 64 + lane];
            xs[i * 4 + 0] = dustM + vv.x;
            xs[i * 4 + 1] = dustM + vv.y;
            xs[i * 4 + 2] = dustM + vv.z;
            xs[i * 4 + 3] = dustM + vv.w;
        }
    }
    float m = xs[0];
#pragma unroll
    for (int i = 1; i < 16; ++i) m = fmaxf(m, xs[i]);
#pragma unroll
    for (int off = 1; off < 64; off <<= 1) m = fmaxf(m, __shfl_xor(m, off));
    float S = 0.f;
#pragma unroll
    for (int i = 0; i < 16; ++i) S += __expf(xs[i] - m);
#pragma unroll
    for (int off = 1; off < 64; off <<= 1) S += __shfl_xor(S, off);
    if (lane == 0) u_out[b * 65 + k] = LOG_A - (m + __logf(S));
}

// ---------------- sinkhorn v-update ----------------------------------------
// 512 blocks = [ns2 0..15][b 0..31] x 256 thr. Thread: token tid&63 of the
// 64-token chunk, k-quarter tid>>6. Coalesced 256B/wave loads; LDS combine.
// UPART=true: first iteration -- combine 16 gemm-emitted chunk partials -> u1.
template<bool UPART>
__global__ __launch_bounds__(256) void sink_v(
    const float* __restrict__ Mmat, const float* __restrict__ u_in,
    const float2* __restrict__ part0,
    const float* __restrict__ dust_p, float* __restrict__ v_out)
{
    __shared__ float us[65];
    __shared__ float2 pp[4][64];
    const int b   = blockIdx.x & 31;
    const int ns2 = blockIdx.x >> 5;         // 0..15
    const int tid = threadIdx.x;
    const int tok = tid & 63, kq = tid >> 6;
    const int n = ns2 * 64 + tok;
    if (tid < 65) {
        if (UPART) {
            const float2* pr = part0 + (size_t)b * 16 * 65 + tid;
            float M2 = -3.4e38f;
            float2 pv[16];
#pragma unroll
            for (int q = 0; q < 16; ++q) { pv[q] = pr[q * 65]; M2 = fmaxf(M2, pv[q].x); }
            float S2 = 0.f;
#pragma unroll
            for (int q = 0; q < 16; ++q) S2 += pv[q].y * __expf(pv[q].x - M2);
            us[tid] = LOG_A - (M2 + __logf(S2));
        } else {
            us[tid] = u_in[b * 65 + tid];
        }
    }
    __syncthreads();
    const float* Mb = Mmat + ((size_t)b * KDIM + kq * 16) * NM1 + n;
    float xs[16];
#pragma unroll
    for (int kk = 0; kk < 16; ++kk) xs[kk] = Mb[(size_t)kk * NM1] + us[kq * 16 + kk];
    float m = xs[0];
#pragma unroll
    for (int kk = 1; kk < 16; ++kk) m = fmaxf(m, xs[kk]);
    float e = 0.f;
#pragma unroll
    for (int kk = 0; kk < 16; ++kk) e += __expf(xs[kk] - m);
    pp[kq][tok] = make_float2(m, e);
    __syncthreads();
    if (tid < 64) {
        const float xd = dust_p[0] * INV_REG + us[64];
        float m3 = xd;
#pragma unroll
        for (int q = 0; q < 4; ++q) m3 = fmaxf(m3, pp[q][tid].x);
        float S3 = __expf(xd - m3);
#pragma unroll
        for (int q = 0; q < 4; ++q) S3 += pp[q][tid].y * __expf(pp[q][tid].x - m3);
        v_out[(size_t)b * NM1 + ns2 * 64 + tid] = LOG_B - (m3 + __logf(S3));
    }
}

// ---------------- aggregation (with fused 5th v-update) ---------------------
// grid (BATCH, NS_AGG) x 256 thr. M-slice in A-frag regs; v5 computed
// block-locally from u5; then p = exp(M+u+v) -> MFMA vs fT B-frags.
__global__ __launch_bounds__(256) void aggregate(
    const float* __restrict__ Mmat, const unsigned short* __restrict__ fT,
    const float* __restrict__ u_in, const float* __restrict__ dust_p,
    float* __restrict__ vpart, float* __restrict__ rspart)
{
    __shared__ float us[65];
    __shared__ __align__(16) float vsh[128];
    __shared__ float wv[4][128][2];
    const int b = blockIdx.x, ns = blockIdx.y;
    const int tid = threadIdx.x;
    const int wave = tid >> 6, lane = tid & 63;
    const int quad = lane >> 4, lrow = lane & 15;
    const int krow = wave * 16 + lrow;
    const float dustM = dust_p[0] * INV_REG;

    if (tid < 65) us[tid] = u_in[b * 65 + tid];
    __syncthreads();

    // ---- M slice into registers (A-frag layout) ----
    float mreg[32];
    {
        const float* Mrow = Mmat + ((size_t)b * KDIM + krow) * NM1 + ns * 128 + quad * 8;
#pragma unroll
        for (int s = 0; s < 4; ++s) {
            float4 a = *(const float4*)(Mrow + s * 32);
            float4 c = *(const float4*)(Mrow + s * 32 + 4);
            mreg[s*8+0]=a.x; mreg[s*8+1]=a.y; mreg[s*8+2]=a.z; mreg[s*8+3]=a.w;
            mreg[s*8+4]=c.x; mreg[s*8+5]=c.y; mreg[s*8+6]=c.z; mreg[s*8+7]=c.w;
        }
    }

    // ---- fused v-update: v5[t] = LOG_B - LSE_k(M[k][t] + u[k]) ----
    const float uk = us[krow];
#pragma unroll
    for (int s = 0; s < 4; ++s) {
#pragma unroll
        for (int j = 0; j < 8; ++j) {
            float x = mreg[s*8+j] + uk;
            float m2 = x;
            m2 = fmaxf(m2, __shfl_xor(m2, 1));
            m2 = fmaxf(m2, __shfl_xor(m2, 2));
            m2 = fmaxf(m2, __shfl_xor(m2, 4));
            m2 = fmaxf(m2, __shfl_xor(m2, 8));
            float e = __expf(x - m2);
            e += __shfl_xor(e, 1);
            e += __shfl_xor(e, 2);
            e += __shfl_xor(e, 4);
            e += __shfl_xor(e, 8);
            if (lrow == 0) {
                wv[wave][s*32 + quad*8 + j][0] = m2;
                wv[wave][s*32 + quad*8 + j][1] = e;
            }
        }
    }
    __syncthreads();
    if (tid < 128) {
        const float xd = dustM + us[64];
        float m3 = xd;
#pragma unroll
        for (int w = 0; w < 4; ++w) m3 = fmaxf(m3, wv[w][tid][0]);
        float S3 = __expf(xd - m3);
#pragma unroll
        for (int w = 0; w < 4; ++w) S3 += wv[w][tid][1] * __expf(wv[w][tid][0] - m3);
        vsh[tid] = LOG_B - (m3 + __logf(S3));
    }
    __syncthreads();

    // ---- p = exp(M+u+v) in A-frag regs, MFMA vs fT B-frags ----
    const unsigned short* fbase = fT + ((size_t)b * CDIM + lrow) * NM1 + ns * 128 + quad * 8;
    floatx4 acc[8];
#pragma unroll
    for (int nf = 0; nf < 8; ++nf) acc[nf] = (floatx4){0.f, 0.f, 0.f, 0.f};
    float rs = 0.f;
#pragma unroll
    for (int s = 0; s < 4; ++s) {
        const int tb = s * 32 + quad * 8;
        float4 v0 = *(const float4*)&vsh[tb];
        float4 v1 = *(const float4*)&vsh[tb + 4];
        float p[8];
        p[0] = __expf(mreg[s*8+0] + uk + v0.x);
        p[1] = __expf(mreg[s*8+1] + uk + v0.y);
        p[2] = __expf(mreg[s*8+2] + uk + v0.z);
        p[3] = __expf(mreg[s*8+3] + uk + v0.w);
        p[4] = __expf(mreg[s*8+4] + uk + v1.x);
        p[5] = __expf(mreg[s*8+5] + uk + v1.y);
        p[6] = __expf(mreg[s*8+6] + uk + v1.z);
        p[7] = __expf(mreg[s*8+7] + uk + v1.w);
        short8 afrag;
#pragma unroll
        for (int j = 0; j < 8; ++j) {
            rs += p[j];
            afrag[j] = (short)bf16_rne(p[j]);
        }
#pragma unroll
        for (int nf = 0; nf < 8; ++nf) {
            short8 bfrag = *(const short8*)(fbase + (size_t)nf * 16 * NM1 + s * 32);
            acc[nf] = __builtin_amdgcn_mfma_f32_16x16x32_bf16(afrag, bfrag, acc[nf], 0, 0, 0);
        }
    }
    rs += __shfl_xor(rs, 16);
    rs += __shfl_xor(rs, 32);
    if (lane < 16) rspart[(ns * BATCH + b) * KDIM + krow] = rs;

    float* vp = vpart + (size_t)(ns * BATCH + b) * (KDIM * CDIM);
#pragma unroll
    for (int nf = 0; nf < 8; ++nf) {
        const int c = nf * 16 + lrow;
#pragma unroll
        for (int j = 0; j < 4; ++j)
            vp[(size_t)(wave * 16 + quad * 4 + j) * CDIM + c] = acc[nf][j];
    }
}

// ---------------- finalize: reduce partials, anchors, L2-normalize ---------
__global__ __launch_bounds__(1024) void finalize_all(
    const float* __restrict__ vpart, const float* __restrict__ rspart,
    const float* __restrict__ anchors, const float* __restrict__ tpart,
    const float* __restrict__ bt, float* __restrict__ out)
{
    __shared__ float rstot[KDIM];
    __shared__ float red[16];
    __shared__ float sc_sh;
    const int b = blockIdx.x, tid = threadIdx.x;
    const int lane = tid & 63, wave = tid >> 6;

    if (tid < KDIM) {
        float s = 0.f;
#pragma unroll
        for (int ns = 0; ns < NS_AGG; ++ns)
            s += rspart[(ns * BATCH + b) * KDIM + tid];
        rstot[tid] = s;
    }
    __syncthreads();

    const size_t e0 = (size_t)tid * 8;
    float4 s0 = make_float4(0.f, 0.f, 0.f, 0.f);
    float4 s1 = make_float4(0.f, 0.f, 0.f, 0.f);
#pragma unroll
    for (int ns = 0; ns < NS_AGG; ++ns) {
        const float* vp = vpart + (size_t)(ns * BATCH + b) * (KDIM * CDIM) + e0;
        float4 a = *(const float4*)(vp);
        float4 c = *(const float4*)(vp + 4);
        s0.x += a.x; s0.y += a.y; s0.z += a.z; s0.w += a.w;
        s1.x += c.x; s1.y += c.y; s1.z += c.z; s1.w += c.w;
    }
    const float rsv = rstot[tid >> 4];
    float4 a0 = *(const float4*)(anchors + e0);
    float4 a1 = *(const float4*)(anchors + e0 + 4);
    float4 v0, v1;
    v0.x = 2.f * s0.x - rsv * a0.x;  v0.y = 2.f * s0.y - rsv * a0.y;
    v0.z = 2.f * s0.z - rsv * a0.z;  v0.w = 2.f * s0.w - rsv * a0.w;
    v1.x = 2.f * s1.x - rsv * a1.x;  v1.y = 2.f * s1.y - rsv * a1.y;
    v1.z = 2.f * s1.z - rsv * a1.z;  v1.w = 2.f * s1.w - rsv * a1.w;
    float ss = v0.x*v0.x + v0.y*v0.y + v0.z*v0.z + v0.w*v0.w
             + v1.x*v1.x + v1.y*v1.y + v1.z*v1.z + v1.w*v1.w;

    float t = 0.f;
    if (tid < TDIM) {
        t = bt[tid];
#pragma unroll
        for (int s = 0; s < 3; ++s) t += tpart[((size_t)s * BATCH + b) * TDIM + tid];
        ss += t * t;
    }

#pragma unroll
    for (int off = 32; off > 0; off >>= 1) ss += __shfl_down(ss, off);
    if (lane == 0) red[wave] = ss;
    __syncthreads();
    if (tid == 0) {
        float tot = 0.f;
#pragma unroll
        for (int i = 0; i < 16; ++i) tot += red[i];
        sc_sh = 1.f / fmaxf(sqrtf(tot), 1e-12f);
    }
    __syncthreads();
    const float scale = sc_sh;

    float* orow = out + (size_t)b * ROWLEN;
    if (tid < TDIM) orow[tid] = t * scale;
    v0.x *= scale; v0.y *= scale; v0.z *= scale; v0.w *= scale;
    v1.x *= scale; v1.y *= scale; v1.z *= scale; v1.w *= scale;
    *(float4*)&orow[TDIM + e0]     = v0;
    *(float4*)&orow[TDIM + e0 + 4] = v1;
}

// ---------------- launcher ----------------
extern "C" void kernel_launch(void* const* d_in, const int* in_sizes, int n_in,
                              void* d_out, int out_size, void* d_ws, size_t ws_size,
                              hipStream_t stream)
{
    const float* x       = (const float*)d_in[0];
    const float* Wf      = (const float*)d_in[1];
    const float* bf      = (const float*)d_in[2];
    const float* Ws      = (const float*)d_in[3];
    const float* bs      = (const float*)d_in[4];
    const float* Wt      = (const float*)d_in[5];
    const float* bt      = (const float*)d_in[6];
    const float* anchors = (const float*)d_in[7];
    const float* dust    = (const float*)d_in[8];
    const float* sharp   = (const float*)d_in[9];
    float* out = (float*)d_out;

    char* base = (char*)d_ws;
    short* W_pack        = (short*)base;                       // 294912 B
    float* bias_all      = (float*)(base + 294912);            // 192 fl
    float* Mmat          = bias_all + 192;                     // 2097152 fl (8.39 MB)
    unsigned short* fT   = (unsigned short*)(Mmat + (size_t)BATCH * KDIM * NM1); // 4194304 us
    float* u_buf         = (float*)(fT + (size_t)BATCH * CDIM * NM1);  // 2080 fl
    float* v_buf         = u_buf + BATCH * 65;                 // 32768 fl
    float2* part0        = (float2*)(v_buf + BATCH * NM1);     // 32*16*65 f2
    float* vpart         = (float*)(part0 + (size_t)BATCH * 16 * 65); // 2097152 fl
    float* rspart        = vpart + (size_t)NS_AGG * BATCH * KDIM * CDIM; // 16384 fl
    float* tpart         = rspart + NS_AGG * BATCH * KDIM;     // 24576 fl

    hipLaunchKernelGGL(prep, dim3(672), dim3(256), 0, stream,
                       Wf, Ws, bf, bs, x, Wt, W_pack, bias_all, tpart);
    hipLaunchKernelGGL(gemm_fs, dim3(512), dim3(256), 0, stream,
                       x, W_pack, bias_all, sharp, dust, fT, Mmat, part0);

    // v1 (u1 combined in-kernel from gemm-emitted partials)
    hipLaunchKernelGGL(HIP_KERNEL_NAME(sink_v<true>), dim3(512), dim3(256), 0, stream,
                       Mmat, u_buf, part0, dust, v_buf);
    // u2..u5 / v2..v4 (v5 fused into aggregate)
    for (int it = 1; it < NITER; ++it) {
        hipLaunchKernelGGL(sink_u, dim3(544), dim3(256), 0, stream,
                           Mmat, v_buf, dust, u_buf);
        if (it < NITER - 1)
            hipLaunchKernelGGL(HIP_KERNEL_NAME(sink_v<false>), dim3(512), dim3(256), 0, stream,
                               Mmat, u_buf, part0, dust, v_buf);
    }

    hipLaunchKernelGGL(aggregate, dim3(BATCH, NS_AGG), dim3(256), 0, stream,
                       Mmat, fT, u_buf, dust, vpart, rspart);
    hipLaunchKernelGGL(finalize_all, dim3(BATCH), dim3(1024), 0, stream,
                       vpart, rspart, anchors, tpart, bt, out);
}

// Round 11
// 232.156 us; speedup vs baseline: 1.0984x; 1.0279x over previous
//
#include <hip/hip_runtime.h>
#include <math.h>

// SALAD head. Round 16: sink_u eliminated. Each sink_vu dispatch: combine 16
// u-partials -> u (65-thread, verified R10 pattern), v-update block-local,
// then emit next u-partials from the SAME M registers via LDS transpose
// yb[64][65] (+1 pad: writes stride-1, reads 2-way=free) + 4-lane shfl merge
// -- no per-row 64-lane butterfly (R8's proven regression). Chain: prep,
// gemm_fs(u1 parts), sink_vu x4, aggregate(16-part combine + v5 + MFMA),
// finalize = 8 dispatches; M-passes 9 -> 5.

#define BATCH 32
#define NTOK  1025
#define DIM   768
#define KDIM  64
#define CDIM  128
#define TDIM  256
#define NM1   1024
#define ROWLEN 8448          // TDIM + KDIM*CDIM
#define NITER 5
#define INV_REG 10.0f        // 1/0.1
#define NS_AGG 8             // n-slices in aggregation (128 tokens each)
#define LOG_A (-4.17438727f) // -log(65)
#define LOG_B (-6.93147181f) // -log(1024)

typedef __attribute__((ext_vector_type(8))) short short8;
typedef __attribute__((ext_vector_type(4))) float floatx4;

typedef __attribute__((address_space(3))) unsigned int lds_uint;
typedef const __attribute__((address_space(1))) unsigned int glb_uint;

__device__ __forceinline__ void gload_lds16(const void* g, void* l) {
    __builtin_amdgcn_global_load_lds((glb_uint*)g, (lds_uint*)l, 16, 0, 0);
}

__device__ __forceinline__ unsigned short bf16_rne(float f) {
    unsigned u = __builtin_bit_cast(unsigned, f);
    unsigned r = u + 0x7FFFu + ((u >> 16) & 1u);
    return (unsigned short)(r >> 16);
}

__device__ __forceinline__ short8 cvt8(float4 a, float4 b) {
    short8 r;
    r[0] = (short)bf16_rne(a.x); r[1] = (short)bf16_rne(a.y);
    r[2] = (short)bf16_rne(a.z); r[3] = (short)bf16_rne(a.w);
    r[4] = (short)bf16_rne(b.x); r[5] = (short)bf16_rne(b.y);
    r[6] = (short)bf16_rne(b.z); r[7] = (short)bf16_rne(b.w);
    return r;
}

// ---------------- prep: pack W (blocks 0..575) + t-GEMM (blocks 576..671) --
__global__ __launch_bounds__(256) void prep(
    const float* __restrict__ Wf, const float* __restrict__ Ws,
    const float* __restrict__ bf, const float* __restrict__ bs,
    const float* __restrict__ x, const float* __restrict__ Wt,
    short* __restrict__ W_pack, float* __restrict__ bias_all,
    float* __restrict__ tpart)
{
    __shared__ float xr[256];
    const int blk = blockIdx.x, tid = threadIdx.x;
    if (blk < 576) {
        int idx = blk * 256 + tid;   // < 147456 exactly
        int g    = idx / 6144;
        int rem  = idx - g * 6144;
        int nf   = rem >> 9;
        int rem2 = rem & 511;
        int lane = rem2 >> 3;
        int j    = rem2 & 7;
        int k = g * 32 + (lane >> 4) * 8 + j;
        int c = nf * 16 + (lane & 15);
        float v = (c < CDIM) ? Wf[(size_t)k * CDIM + c] : Ws[(size_t)k * KDIM + (c - CDIM)];
        W_pack[idx] = (short)bf16_rne(v);
        if (idx < 192) bias_all[idx] = (idx < CDIM) ? bf[idx] : bs[idx - CDIM];
    } else {
        int i = blk - 576;           // 0..95
        int b = i / 3, dy = i - b * 3;
        xr[tid] = x[(size_t)b * NTOK * DIM + (size_t)dy * 256 + tid];
        __syncthreads();
        float acc = 0.f;
        const float* wp = Wt + (size_t)dy * 256 * TDIM + tid;
#pragma unroll 8
        for (int d = 0; d < 256; ++d) acc = fmaf(xr[d], wp[(size_t)d * TDIM], acc);
        tpart[((size_t)dy * BATCH + b) * TDIM + tid] = acc;
    }
}

// ---------------- fused f / s GEMM via MFMA + LDS staging -------------------
// R10's verified kernel: prefetch-after-barrier schedule + u1-partial
// emission (v0=0) into part0[b][chunk][65]; dust partial (dustM, 64).
__global__ __launch_bounds__(256, 2) void gemm_fs(
    const float* __restrict__ x, const short* __restrict__ W_pack,
    const float* __restrict__ bias_all, const float* __restrict__ sharp_p,
    const float* __restrict__ dust_p,
    unsigned short* __restrict__ fT, float* __restrict__ Mmat,
    float2* __restrict__ part0)
{
    __shared__ __align__(16) short Bs[12288];  // 24 KB
    __shared__ __align__(16) short As[4096];   //  8 KB
    __shared__ float2 sm[4][4][16];            //  2 KB  [wave][nf-8][lrow]
    const int tid  = threadIdx.x;
    const int wave = tid >> 6, lane = tid & 63;
    const int quad = lane >> 4, lrow = lane & 15;
    const int bb0   = blockIdx.x & 31;
    const int chunk = blockIdx.x >> 5;       // 0..15
    const int R = bb0 * 1024 + chunk * 64 + wave * 16;

    const int arow = bb0 * 1024 + chunk * 64 + (tid >> 2);
    const float* asrc = x + ((size_t)(arow >> 10) * NTOK + 1 + (arow & 1023)) * DIM + (tid & 3) * 16;
    const int r    = (tid >> 2) & 15;
    const int seg  = tid & 3;
    const int kk_w = seg >> 1;
    const int q0   = (seg & 1) * 2;
    short* adst0 = &As[(((tid >> 6) * 2 + kk_w) * 64 + q0 * 16 + r) * 8];
    short* adst1 = &As[(((tid >> 6) * 2 + kk_w) * 64 + (q0 + 1) * 16 + r) * 8];

    floatx4 acc[12];
#pragma unroll
    for (int nf = 0; nf < 12; ++nf) acc[nf] = (floatx4){0.f, 0.f, 0.f, 0.f};

    float4 g0 = *(const float4*)(asrc);
    float4 g1 = *(const float4*)(asrc + 4);
    float4 g2 = *(const float4*)(asrc + 8);
    float4 g3 = *(const float4*)(asrc + 12);

    for (int ko = 0; ko < 12; ++ko) {
        __syncthreads();
        const short* bsrc = W_pack + ko * 12288 + tid * 8;
#pragma unroll
        for (int i = 0; i < 6; ++i)
            gload_lds16(bsrc + i * 2048, &Bs[i * 2048 + tid * 8]);
        *(short8*)adst0 = cvt8(g0, g1);
        *(short8*)adst1 = cvt8(g2, g3);
        __syncthreads();
        if (ko < 11) {
            // prefetch next x k-slice after the barrier: HBM latency overlaps
            // the MFMA phase; drained by NEXT iteration's barrier.
            const float* ap = asrc + (ko + 1) * 64;
            g0 = *(const float4*)(ap);
            g1 = *(const float4*)(ap + 4);
            g2 = *(const float4*)(ap + 8);
            g3 = *(const float4*)(ap + 12);
            __builtin_amdgcn_sched_barrier(0);  // loads may not sink below
        }
#pragma unroll
        for (int kk = 0; kk < 2; ++kk) {
            short8 af = *(const short8*)&As[((wave * 2 + kk) * 64 + lane) * 8];
#pragma unroll
            for (int nf = 0; nf < 12; ++nf) {
                short8 bf8 = *(const short8*)&Bs[((kk * 12 + nf) * 64 + lane) * 8];
                acc[nf] = __builtin_amdgcn_mfma_f32_16x16x32_bf16(af, bf8, acc[nf], 0, 0, 0);
            }
        }
    }

    const float sc = sharp_p[0] * INV_REG;
    const float dustM = dust_p[0] * INV_REG;
    const int bb = R >> 10;
    const int tok = (R & 1023) + quad * 4;
#pragma unroll
    for (int nf = 0; nf < 12; ++nf) {
        const int c = nf * 16 + lrow;
        const float bias = bias_all[c];
        if (nf < 8) {
            ushort4 w;
            w.x = bf16_rne(acc[nf][0] + bias);
            w.y = bf16_rne(acc[nf][1] + bias);
            w.z = bf16_rne(acc[nf][2] + bias);
            w.w = bf16_rne(acc[nf][3] + bias);
            *(ushort4*)(fT + ((size_t)bb * CDIM + c) * NM1 + tok) = w;
        } else {
            const int k = c - CDIM;
            float4 w = make_float4((acc[nf][0] + bias) * sc, (acc[nf][1] + bias) * sc,
                                   (acc[nf][2] + bias) * sc, (acc[nf][3] + bias) * sc);
            *(float4*)(Mmat + ((size_t)bb * KDIM + k) * NM1 + tok) = w;
            // u1-partial: row-LSE over this wave's 16 tokens (v0 = 0)
            float m = fmaxf(fmaxf(w.x, w.y), fmaxf(w.z, w.w));
            m = fmaxf(m, __shfl_xor(m, 16));
            m = fmaxf(m, __shfl_xor(m, 32));
            float e = __expf(w.x - m) + __expf(w.y - m)
                    + __expf(w.z - m) + __expf(w.w - m);
            e += __shfl_xor(e, 16);
            e += __shfl_xor(e, 32);
            if (quad == 0) sm[wave][nf - 8][lrow] = make_float2(m, e);
        }
    }
    __syncthreads();
    // combine 4 wave-partials (64 tokens) -> part0[b][chunk][k]
    if (tid < 65) {
        float2 o;
        if (tid < 64) {
            float2 p0 = sm[0][tid >> 4][tid & 15];
            float2 p1 = sm[1][tid >> 4][tid & 15];
            float2 p2 = sm[2][tid >> 4][tid & 15];
            float2 p3 = sm[3][tid >> 4][tid & 15];
            float m = fmaxf(fmaxf(p0.x, p1.x), fmaxf(p2.x, p3.x));
            float e = p0.y * __expf(p0.x - m) + p1.y * __expf(p1.x - m)
                    + p2.y * __expf(p2.x - m) + p3.y * __expf(p3.x - m);
            o = make_float2(m, e);
        } else {
            o = make_float2(dustM, 64.f);   // dust row, v0=0: 64 tokens exp(0)
        }
        part0[((size_t)bb0 * 16 + chunk) * 65 + tid] = o;
    }
}

// ---------------- sink_vu: one dispatch per sinkhorn iteration --------------
// 512 blocks = [ns2 0..15][b 0..31] x 256 thr. Thread (tok = tid&63,
// kq = tid>>6). Phase 1: combine 16 u-partials -> us[65]. Phase 2: v-update
// (coalesced M in regs, 4-way LDS combine + dust). Phase 3: emit next
// u-partials: y = M + v via LDS transpose yb[64][65], 4-lane shfl (m,e)
// merge; dust partial from wave-0 butterfly over vsh.
__global__ __launch_bounds__(256) void sink_vu(
    const float* __restrict__ Mmat, const float* __restrict__ dust_p,
    const float2* __restrict__ pin, float2* __restrict__ pout)
{
    __shared__ float us[65];
    __shared__ float2 pp[4][64];
    __shared__ float vsh[64];
    __shared__ float yb[64][65];
    const int b   = blockIdx.x & 31;
    const int ns2 = blockIdx.x >> 5;         // 0..15
    const int tid = threadIdx.x;
    const int tok = tid & 63, kq = tid >> 6;
    const int n = ns2 * 64 + tok;
    const float dustM = dust_p[0] * INV_REG;

    // coalesced M loads: mreg[kk] = M[b][kq*16+kk][n]
    float mreg[16];
    const float* Mb = Mmat + ((size_t)b * KDIM + kq * 16) * NM1 + n;
#pragma unroll
    for (int kk = 0; kk < 16; ++kk) mreg[kk] = Mb[(size_t)kk * NM1];

    // ---- phase 1: u-combine (16 chunk partials) ----
    if (tid < 65) {
        const float2* pr = pin + (size_t)b * 16 * 65 + tid;
        float M2 = -3.4e38f;
        float2 pv[16];
#pragma unroll
        for (int q = 0; q < 16; ++q) { pv[q] = pr[q * 65]; M2 = fmaxf(M2, pv[q].x); }
        float S2 = 0.f;
#pragma unroll
        for (int q = 0; q < 16; ++q) S2 += pv[q].y * __expf(pv[q].x - M2);
        us[tid] = LOG_A - (M2 + __logf(S2));
    }
    __syncthreads();

    // ---- phase 2: v-update ----
    {
        float m = mreg[0] + us[kq * 16];
#pragma unroll
        for (int kk = 1; kk < 16; ++kk) m = fmaxf(m, mreg[kk] + us[kq * 16 + kk]);
        float e = 0.f;
#pragma unroll
        for (int kk = 0; kk < 16; ++kk) e += __expf(mreg[kk] + us[kq * 16 + kk] - m);
        pp[kq][tok] = make_float2(m, e);
    }
    __syncthreads();
    if (tid < 64) {
        const float xd = dustM + us[64];
        float m3 = xd;
#pragma unroll
        for (int q = 0; q < 4; ++q) m3 = fmaxf(m3, pp[q][tid].x);
        float S3 = __expf(xd - m3);
#pragma unroll
        for (int q = 0; q < 4; ++q) S3 += pp[q][tid].y * __expf(pp[q][tid].x - m3);
        vsh[tid] = LOG_B - (m3 + __logf(S3));
    }
    __syncthreads();

    // ---- phase 3: emit next u-partials ----
    const float v = vsh[tok];
#pragma unroll
    for (int kk = 0; kk < 16; ++kk) yb[kq * 16 + kk][tok] = mreg[kk] + v;
    // dust partial: LSE over this block's 64 tokens of (dustM + v[t]); wave 0
    if (kq == 0) {
        float mv = v;
#pragma unroll
        for (int off = 1; off < 64; off <<= 1) mv = fmaxf(mv, __shfl_xor(mv, off));
        float ev = __expf(v - mv);
#pragma unroll
        for (int off = 1; off < 64; off <<= 1) ev += __shfl_xor(ev, off);
        if (tok == 0) pout[((size_t)b * 16 + ns2) * 65 + 64] = make_float2(dustM + mv, ev);
    }
    __syncthreads();
    // transposed per-row reduce: row r = tid>>2 (0..63), quarter tq = tid&3
    {
        const int rr = tid >> 2, tq = tid & 3;
        float mm = yb[rr][tq * 16];
#pragma unroll
        for (int i = 1; i < 16; ++i) mm = fmaxf(mm, yb[rr][tq * 16 + i]);
        float ee = 0.f;
#pragma unroll
        for (int i = 0; i < 16; ++i) ee += __expf(yb[rr][tq * 16 + i] - mm);
        // merge (m,e) across the 4 same-row lanes (consecutive, same wave)
        float m1 = __shfl_xor(mm, 1), e1 = __shfl_xor(ee, 1);
        float mo = fmaxf(mm, m1);
        ee = ee * __expf(mm - mo) + e1 * __expf(m1 - mo); mm = mo;
        float m2 = __shfl_xor(mm, 2), e2 = __shfl_xor(ee, 2);
        mo = fmaxf(mm, m2);
        ee = ee * __expf(mm - mo) + e2 * __expf(m2 - mo); mm = mo;
        if (tq == 0) pout[((size_t)b * 16 + ns2) * 65 + rr] = make_float2(mm, ee);
    }
}

// ---------------- aggregation: u5-combine (16 parts) + v5 + MFMA ------------
// grid (BATCH, NS_AGG) x 256 thr. M-slice in A-frag regs; v5 computed
// block-locally from u5; then p = exp(M+u+v) -> MFMA vs fT B-frags.
__global__ __launch_bounds__(256) void aggregate(
    const float* __restrict__ Mmat, const unsigned short* __restrict__ fT,
    const float2* __restrict__ pin, const float* __restrict__ dust_p,
    float* __restrict__ vpart, float* __restrict__ rspart)
{
    __shared__ float us[65];
    __shared__ __align__(16) float vsh[128];
    __shared__ float wv[4][128][2];
    const int b = blockIdx.x, ns = blockIdx.y;
    const int tid = threadIdx.x;
    const int wave = tid >> 6, lane = tid & 63;
    const int quad = lane >> 4, lrow = lane & 15;
    const int krow = wave * 16 + lrow;
    const float dustM = dust_p[0] * INV_REG;

    // ---- u5 combine (16 chunk partials) ----
    if (tid < 65) {
        const float2* pr = pin + (size_t)b * 16 * 65 + tid;
        float M2 = -3.4e38f;
        float2 pv[16];
#pragma unroll
        for (int q = 0; q < 16; ++q) { pv[q] = pr[q * 65]; M2 = fmaxf(M2, pv[q].x); }
        float S2 = 0.f;
#pragma unroll
        for (int q = 0; q < 16; ++q) S2 += pv[q].y * __expf(pv[q].x - M2);
        us[tid] = LOG_A - (M2 + __logf(S2));
    }
    __syncthreads();

    // ---- M slice into registers (A-frag layout) ----
    float mreg[32];
    {
        const float* Mrow = Mmat + ((size_t)b * KDIM + krow) * NM1 + ns * 128 + quad * 8;
#pragma unroll
        for (int s = 0; s < 4; ++s) {
            float4 a = *(const float4*)(Mrow + s * 32);
            float4 c = *(const float4*)(Mrow + s * 32 + 4);
            mreg[s*8+0]=a.x; mreg[s*8+1]=a.y; mreg[s*8+2]=a.z; mreg[s*8+3]=a.w;
            mreg[s*8+4]=c.x; mreg[s*8+5]=c.y; mreg[s*8+6]=c.z; mreg[s*8+7]=c.w;
        }
    }

    // ---- fused v5: v[t] = LOG_B - LSE_k(M[k][t] + u[k]) ----
    const float uk = us[krow];
#pragma unroll
    for (int s = 0; s < 4; ++s) {
#pragma unroll
        for (int j = 0; j < 8; ++j) {
            float x = mreg[s*8+j] + uk;
            float m2 = x;
            m2 = fmaxf(m2, __shfl_xor(m2, 1));
            m2 = fmaxf(m2, __shfl_xor(m2, 2));
            m2 = fmaxf(m2, __shfl_xor(m2, 4));
            m2 = fmaxf(m2, __shfl_xor(m2, 8));
            float e = __expf(x - m2);
            e += __shfl_xor(e, 1);
            e += __shfl_xor(e, 2);
            e += __shfl_xor(e, 4);
            e += __shfl_xor(e, 8);
            if (lrow == 0) {
                wv[wave][s*32 + quad*8 + j][0] = m2;
                wv[wave][s*32 + quad*8 + j][1] = e;
            }
        }
    }
    __syncthreads();
    if (tid < 128) {
        const float xd = dustM + us[64];
        float m3 = xd;
#pragma unroll
        for (int w = 0; w < 4; ++w) m3 = fmaxf(m3, wv[w][tid][0]);
        float S3 = __expf(xd - m3);
#pragma unroll
        for (int w = 0; w < 4; ++w) S3 += wv[w][tid][1] * __expf(wv[w][tid][0] - m3);
        vsh[tid] = LOG_B - (m3 + __logf(S3));
    }
    __syncthreads();

    // ---- p = exp(M+u+v) in A-frag regs, MFMA vs fT B-frags ----
    const unsigned short* fbase = fT + ((size_t)b * CDIM + lrow) * NM1 + ns * 128 + quad * 8;
    floatx4 acc[8];
#pragma unroll
    for (int nf = 0; nf < 8; ++nf) acc[nf] = (floatx4){0.f, 0.f, 0.f, 0.f};
    float rs = 0.f;
#pragma unroll
    for (int s = 0; s < 4; ++s) {
        const int tb = s * 32 + quad * 8;
        float4 v0 = *(const float4*)&vsh[tb];
        float4 v1 = *(const float4*)&vsh[tb + 4];
        float p[8];
        p[0] = __expf(mreg[s*8+0] + uk + v0.x);
        p[1] = __expf(mreg[s*8+1] + uk + v0.y);
        p[2] = __expf(mreg[s*8+2] + uk + v0.z);
        p[3] = __expf(mreg[s*8+3] + uk + v0.w);
        p[4] = __expf(mreg[s*8+4] + uk + v1.x);
        p[5] = __expf(mreg[s*8+5] + uk + v1.y);
        p[6] = __expf(mreg[s*8+6] + uk + v1.z);
        p[7] = __expf(mreg[s*8+7] + uk + v1.w);
        short8 afrag;
#pragma unroll
        for (int j = 0; j < 8; ++j) {
            rs += p[j];
            afrag[j] = (short)bf16_rne(p[j]);
        }
#pragma unroll
        for (int nf = 0; nf < 8; ++nf) {
            short8 bfrag = *(const short8*)(fbase + (size_t)nf * 16 * NM1 + s * 32);
            acc[nf] = __builtin_amdgcn_mfma_f32_16x16x32_bf16(afrag, bfrag, acc[nf], 0, 0, 0);
        }
    }
    rs += __shfl_xor(rs, 16);
    rs += __shfl_xor(rs, 32);
    if (lane < 16) rspart[(ns * BATCH + b) * KDIM + krow] = rs;

    float* vp = vpart + (size_t)(ns * BATCH + b) * (KDIM * CDIM);
#pragma unroll
    for (int nf = 0; nf < 8; ++nf) {
        const int c = nf * 16 + lrow;
#pragma unroll
        for (int j = 0; j < 4; ++j)
            vp[(size_t)(wave * 16 + quad * 4 + j) * CDIM + c] = acc[nf][j];
    }
}

// ---------------- finalize: reduce partials, anchors, L2-normalize ---------
__global__ __launch_bounds__(1024) void finalize_all(
    const float* __restrict__ vpart, const float* __restrict__ rspart,
    const float* __restrict__ anchors, const float* __restrict__ tpart,
    const float* __restrict__ bt, float* __restrict__ out)
{
    __shared__ float rstot[KDIM];
    __shared__ float red[16];
    __shared__ float sc_sh;
    const int b = blockIdx.x, tid = threadIdx.x;
    const int lane = tid & 63, wave = tid >> 6;

    if (tid < KDIM) {
        float s = 0.f;
#pragma unroll
        for (int ns = 0; ns < NS_AGG; ++ns)
            s += rspart[(ns * BATCH + b) * KDIM + tid];
        rstot[tid] = s;
    }
    __syncthreads();

    const size_t e0 = (size_t)tid * 8;
    float4 s0 = make_float4(0.f, 0.f, 0.f, 0.f);
    float4 s1 = make_float4(0.f, 0.f, 0.f, 0.f);
#pragma unroll
    for (int ns = 0; ns < NS_AGG; ++ns) {
        const float* vp = vpart + (size_t)(ns * BATCH + b) * (KDIM * CDIM) + e0;
        float4 a = *(const float4*)(vp);
        float4 c = *(const float4*)(vp + 4);
        s0.x += a.x; s0.y += a.y; s0.z += a.z; s0.w += a.w;
        s1.x += c.x; s1.y += c.y; s1.z += c.z; s1.w += c.w;
    }
    const float rsv = rstot[tid >> 4];
    float4 a0 = *(const float4*)(anchors + e0);
    float4 a1 = *(const float4*)(anchors + e0 + 4);
    float4 v0, v1;
    v0.x = 2.f * s0.x - rsv * a0.x;  v0.y = 2.f * s0.y - rsv * a0.y;
    v0.z = 2.f * s0.z - rsv * a0.z;  v0.w = 2.f * s0.w - rsv * a0.w;
    v1.x = 2.f * s1.x - rsv * a1.x;  v1.y = 2.f * s1.y - rsv * a1.y;
    v1.z = 2.f * s1.z - rsv * a1.z;  v1.w = 2.f * s1.w - rsv * a1.w;
    float ss = v0.x*v0.x + v0.y*v0.y + v0.z*v0.z + v0.w*v0.w
             + v1.x*v1.x + v1.y*v1.y + v1.z*v1.z + v1.w*v1.w;

    float t = 0.f;
    if (tid < TDIM) {
        t = bt[tid];
#pragma unroll
        for (int s = 0; s < 3; ++s) t += tpart[((size_t)s * BATCH + b) * TDIM + tid];
        ss += t * t;
    }

#pragma unroll
    for (int off = 32; off > 0; off >>= 1) ss += __shfl_down(ss, off);
    if (lane == 0) red[wave] = ss;
    __syncthreads();
    if (tid == 0) {
        float tot = 0.f;
#pragma unroll
        for (int i = 0; i < 16; ++i) tot += red[i];
        sc_sh = 1.f / fmaxf(sqrtf(tot), 1e-12f);
    }
    __syncthreads();
    const float scale = sc_sh;

    float* orow = out + (size_t)b * ROWLEN;
    if (tid < TDIM) orow[tid] = t * scale;
    v0.x *= scale; v0.y *= scale; v0.z *= scale; v0.w *= scale;
    v1.x *= scale; v1.y *= scale; v1.z *= scale; v1.w *= scale;
    *(float4*)&orow[TDIM + e0]     = v0;
    *(float4*)&orow[TDIM + e0 + 4] = v1;
}

// ---------------- launcher ----------------
extern "C" void kernel_launch(void* const* d_in, const int* in_sizes, int n_in,
                              void* d_out, int out_size, void* d_ws, size_t ws_size,
                              hipStream_t stream)
{
    const float* x       = (const float*)d_in[0];
    const float* Wf      = (const float*)d_in[1];
    const float* bf      = (const float*)d_in[2];
    const float* Ws      = (const float*)d_in[3];
    const float* bs      = (const float*)d_in[4];
    const float* Wt      = (const float*)d_in[5];
    const float* bt      = (const float*)d_in[6];
    const float* anchors = (const float*)d_in[7];
    const float* dust    = (const float*)d_in[8];
    const float* sharp   = (const float*)d_in[9];
    float* out = (float*)d_out;

    char* base = (char*)d_ws;
    short* W_pack        = (short*)base;                       // 294912 B
    float* bias_all      = (float*)(base + 294912);            // 192 fl
    float* Mmat          = bias_all + 192;                     // 2097152 fl (8.39 MB)
    unsigned short* fT   = (unsigned short*)(Mmat + (size_t)BATCH * KDIM * NM1); // 4194304 us
    float2* part0        = (float2*)(fT + (size_t)BATCH * CDIM * NM1); // 32*16*65 f2
    float2* part1        = part0 + (size_t)BATCH * 16 * 65;
    float* vpart         = (float*)(part1 + (size_t)BATCH * 16 * 65); // 2097152 fl
    float* rspart        = vpart + (size_t)NS_AGG * BATCH * KDIM * CDIM; // 16384 fl
    float* tpart         = rspart + NS_AGG * BATCH * KDIM;     // 24576 fl

    hipLaunchKernelGGL(prep, dim3(672), dim3(256), 0, stream,
                       Wf, Ws, bf, bs, x, Wt, W_pack, bias_all, tpart);
    hipLaunchKernelGGL(gemm_fs, dim3(512), dim3(256), 0, stream,
                       x, W_pack, bias_all, sharp, dust, fT, Mmat, part0);

    // 4 fused iterations: combine u_it, compute v_it, emit u_{it+1}-partials
    hipLaunchKernelGGL(sink_vu, dim3(512), dim3(256), 0, stream,
                       Mmat, dust, part0, part1);
    hipLaunchKernelGGL(sink_vu, dim3(512), dim3(256), 0, stream,
                       Mmat, dust, part1, part0);
    hipLaunchKernelGGL(sink_vu, dim3(512), dim3(256), 0, stream,
                       Mmat, dust, part0, part1);
    hipLaunchKernelGGL(sink_vu, dim3(512), dim3(256), 0, stream,
                       Mmat, dust, part1, part0);

    // u5 combine + v5 + aggregation MFMA
    hipLaunchKernelGGL(aggregate, dim3(BATCH, NS_AGG), dim3(256), 0, stream,
                       Mmat, fT, part0, dust, vpart, rspart);
    hipLaunchKernelGGL(finalize_all, dim3(BATCH), dim3(1024), 0, stream,
                       vpart, rspart, anchors, tpart, bt, out);
}